// Round 1
// baseline (4156.984 us; speedup 1.0000x reference)
//
#include <hip/hip_runtime.h>
#include <hip/hip_bf16.h>
#include <cstdint>

// ---------------- constants ----------------
#define LQ 900
#define BB 16
#define CC 256
#define MM 8
#define CV 32
#define NROWS (LQ * BB)   // 14400

// level geometry (square levels)
__device__ __constant__ int d_HW[4]    = {100, 50, 25, 13};
__device__ __constant__ int d_baseR[4] = {0, 160000, 200000, 210000};

// ---------------- generic tiled fp32 GEMM ----------------
// C[M,N] = (A (+A2)) @ B + bias (+resid) (opt relu). A row-major (lda),
// B row-major (ldb, pointer pre-offset for column blocks), C row-major (ldc).
#define TS 64
#define KS 16

template<bool ADD_A2, bool RELU, bool RESID>
__global__ __launch_bounds__(256) void gemm_f32(
    const float* __restrict__ A, const float* __restrict__ A2, int lda,
    const float* __restrict__ Bm, int ldb, const float* __restrict__ bias,
    const float* __restrict__ resid, float* __restrict__ C, int ldc,
    int Mr, int Nc, int Kd)
{
    __shared__ float As[KS][TS];
    __shared__ float Bs[KS][TS];
    const int t  = threadIdx.x;
    const int tx = t & 15, ty = t >> 4;
    const int row0 = blockIdx.y * TS;
    const int col0 = blockIdx.x * TS;

    float acc[4][4] = {};

    const int ar = t >> 2, ak = (t & 3) * 4;   // A tile loader: row ar, k ak..ak+3
    const int bk = t >> 4, bn = (t & 15) * 4;  // B tile loader: k bk, col bn..bn+3
    const int arow  = row0 + ar;
    const int arowc = arow < Mr ? arow : (Mr - 1);

    for (int k0 = 0; k0 < Kd; k0 += KS) {
        float4 av = *reinterpret_cast<const float4*>(A + (size_t)arowc * lda + k0 + ak);
        if (ADD_A2) {
            const float4 a2 = *reinterpret_cast<const float4*>(A2 + (size_t)arowc * lda + k0 + ak);
            av.x += a2.x; av.y += a2.y; av.z += a2.z; av.w += a2.w;
        }
        As[ak + 0][ar] = av.x; As[ak + 1][ar] = av.y;
        As[ak + 2][ar] = av.z; As[ak + 3][ar] = av.w;
        *reinterpret_cast<float4*>(&Bs[bk][bn]) =
            *reinterpret_cast<const float4*>(Bm + (size_t)(k0 + bk) * ldb + col0 + bn);
        __syncthreads();

        #pragma unroll
        for (int kk = 0; kk < KS; ++kk) {
            const float4 a4 = *reinterpret_cast<const float4*>(&As[kk][ty * 4]);
            const float4 b4 = *reinterpret_cast<const float4*>(&Bs[kk][tx * 4]);
            const float aa[4] = {a4.x, a4.y, a4.z, a4.w};
            const float bb[4] = {b4.x, b4.y, b4.z, b4.w};
            #pragma unroll
            for (int i = 0; i < 4; ++i)
                #pragma unroll
                for (int j = 0; j < 4; ++j)
                    acc[i][j] += aa[i] * bb[j];
        }
        __syncthreads();
    }

    #pragma unroll
    for (int i = 0; i < 4; ++i) {
        const int r = row0 + ty * 4 + i;
        if (r >= Mr) continue;
        #pragma unroll
        for (int j = 0; j < 4; ++j) {
            const int c = col0 + tx * 4 + j;
            float v = acc[i][j] + bias[c];
            if (RESID) v += resid[(size_t)r * ldc + c];
            if (RELU)  v = fmaxf(v, 0.f);
            C[(size_t)r * ldc + c] = v;
        }
    }
}

// ---------------- MHA: flash-style, one wave per (b,m,q) row ----------------
// QK: (14400, 512) rows q*16+b; cols 0..255 = Q (m*32+d), 256..511 = K.
// Vbuf: (14400, 256).  Out attnO: (14400, 256) col m*32+d.
__global__ __launch_bounds__(256) void attn_kernel(
    const float* __restrict__ QK, const float* __restrict__ Vbuf,
    float* __restrict__ attnO)
{
    const int wid  = blockIdx.x * 4 + (threadIdx.x >> 6);
    const int lane = threadIdx.x & 63;
    const int q  = wid % LQ;
    const int bm = wid / LQ;          // = b*8 + m  (consecutive waves share b,m -> L2 reuse of K/V)
    const int m  = bm & 7, b = bm >> 3;

    const float scale = 0.17677669529663687f; // 1/sqrt(32)
    float qreg[32];
    const float* qp = QK + ((size_t)q * BB + b) * 512 + m * 32;
    #pragma unroll
    for (int d0 = 0; d0 < 32; d0 += 4) {
        const float4 t4 = *reinterpret_cast<const float4*>(qp + d0);
        qreg[d0] = t4.x * scale; qreg[d0 + 1] = t4.y * scale;
        qreg[d0 + 2] = t4.z * scale; qreg[d0 + 3] = t4.w * scale;
    }

    float ml = -1e30f, lsum = 0.f;
    float acc[32] = {};
    for (int kk = lane; kk < LQ; kk += 64) {
        const float* kp = QK   + ((size_t)kk * BB + b) * 512 + 256 + m * 32;
        const float* vp = Vbuf + ((size_t)kk * BB + b) * 256 + m * 32;
        float s = 0.f;
        #pragma unroll
        for (int d0 = 0; d0 < 32; d0 += 4) {
            const float4 k4 = *reinterpret_cast<const float4*>(kp + d0);
            s += qreg[d0] * k4.x + qreg[d0 + 1] * k4.y
               + qreg[d0 + 2] * k4.z + qreg[d0 + 3] * k4.w;
        }
        const float mnew = fmaxf(ml, s);
        const float p    = __expf(s - mnew);
        const float corr = __expf(ml - mnew);
        lsum = lsum * corr + p;
        #pragma unroll
        for (int d0 = 0; d0 < 32; d0 += 4) {
            const float4 v4 = *reinterpret_cast<const float4*>(vp + d0);
            acc[d0]     = acc[d0]     * corr + p * v4.x;
            acc[d0 + 1] = acc[d0 + 1] * corr + p * v4.y;
            acc[d0 + 2] = acc[d0 + 2] * corr + p * v4.z;
            acc[d0 + 3] = acc[d0 + 3] * corr + p * v4.w;
        }
        ml = mnew;
    }

    // cross-lane combine
    float Mw = ml;
    #pragma unroll
    for (int o = 32; o; o >>= 1) Mw = fmaxf(Mw, __shfl_xor(Mw, o));
    const float f = __expf(ml - Mw);
    float lw = lsum * f;
    #pragma unroll
    for (int o = 32; o; o >>= 1) lw += __shfl_xor(lw, o);

    float outv = 0.f;
    #pragma unroll
    for (int d = 0; d < 32; ++d) {
        float s = acc[d] * f;
        #pragma unroll
        for (int o = 32; o; o >>= 1) s += __shfl_xor(s, o);
        if ((lane & 31) == d) outv = s;
    }
    if (lane < 32)
        attnO[((size_t)q * BB + b) * 256 + m * 32 + lane] = outv / lw;
}

// ---------------- layernorm: one wave per row of 256 ----------------
__global__ __launch_bounds__(256) void ln_kernel(
    const float* __restrict__ X, const float* __restrict__ g,
    const float* __restrict__ bta, float* __restrict__ Y, int nrows)
{
    const int r = blockIdx.x * 4 + (threadIdx.x >> 6);
    if (r >= nrows) return;
    const int lane = threadIdx.x & 63;
    const float4 v = *reinterpret_cast<const float4*>(X + (size_t)r * 256 + lane * 4);
    float s  = v.x + v.y + v.z + v.w;
    float sq = v.x * v.x + v.y * v.y + v.z * v.z + v.w * v.w;
    #pragma unroll
    for (int o = 32; o; o >>= 1) { s += __shfl_xor(s, o); sq += __shfl_xor(sq, o); }
    const float mean = s * (1.f / 256.f);
    const float var  = sq * (1.f / 256.f) - mean * mean;
    const float rs   = rsqrtf(var + 1e-5f);
    const float4 gv = *reinterpret_cast<const float4*>(g + lane * 4);
    const float4 bv = *reinterpret_cast<const float4*>(bta + lane * 4);
    float4 o4;
    o4.x = (v.x - mean) * rs * gv.x + bv.x;
    o4.y = (v.y - mean) * rs * gv.y + bv.y;
    o4.z = (v.z - mean) * rs * gv.z + bv.z;
    o4.w = (v.w - mean) * rs * gv.w + bv.w;
    *reinterpret_cast<float4*>(Y + (size_t)r * 256 + lane * 4) = o4;
}

// ---------------- per-(row,m) softmax over L*K=16 attention weights ----------------
__global__ __launch_bounds__(256) void aw_softmax(float* __restrict__ awr)
{
    const int gid = blockIdx.x * 256 + threadIdx.x;
    if (gid >= NROWS * MM) return;
    const int row = gid >> 3, m = gid & 7;
    float* p = awr + (size_t)row * 128 + m * 16;
    float v[16], mx = -1e30f;
    #pragma unroll
    for (int i = 0; i < 16; ++i) { v[i] = p[i]; mx = fmaxf(mx, v[i]); }
    float s = 0.f;
    #pragma unroll
    for (int i = 0; i < 16; ++i) { v[i] = __expf(v[i] - mx); s += v[i]; }
    const float inv = 1.f / s;
    #pragma unroll
    for (int i = 0; i < 16; ++i) p[i] = v[i] * inv;
}

// ---------------- deformable bilinear sampling ----------------
// one wave per (b,m,q): lane = (kh*32 + d); kh picks k in {kh*2, kh*2+1}
__global__ __launch_bounds__(256) void sample_kernel(
    const float* __restrict__ Vval, const float* __restrict__ offb,
    const float* __restrict__ aw, const float* __restrict__ ref,
    float* __restrict__ samp)
{
    const int wid  = blockIdx.x * 4 + (threadIdx.x >> 6);
    const int lane = threadIdx.x & 63;
    const int q  = wid % LQ;
    const int bm = wid / LQ;
    const int m  = bm & 7, b = bm >> 3;
    const int d  = lane & 31, kh = lane >> 5;
    const int row = q * BB + b;

    const float rx = ref[row * 2 + 0];
    const float ry = ref[row * 2 + 1];

    float acc = 0.f;
    #pragma unroll
    for (int l = 0; l < 4; ++l) {
        const int   Hl = d_HW[l];
        const float Hf = (float)Hl;
        const float* Vl = Vval + ((size_t)d_baseR[l] + (size_t)b * Hl * Hl) * 256 + m * 32 + d;
        #pragma unroll
        for (int k2 = 0; k2 < 2; ++k2) {
            const int k = kh * 2 + k2;
            const float ox  = offb[(size_t)row * 256 + m * 32 + l * 8 + k * 2 + 0];
            const float oy  = offb[(size_t)row * 256 + m * 32 + l * 8 + k * 2 + 1];
            const float awv = aw[(size_t)row * 128 + m * 16 + l * 4 + k];
            const float px = rx * Hf - 0.5f + ox;
            const float py = ry * Hf - 0.5f + oy;
            const float x0 = floorf(px), y0 = floorf(py);
            #pragma unroll
            for (int c = 0; c < 4; ++c) {
                const float xi = x0 + (float)(c & 1);
                const float yi = y0 + (float)(c >> 1);
                const float w = (1.f - fabsf(px - xi)) * (1.f - fabsf(py - yi));
                const bool valid = (xi >= 0.f) && (xi < Hf) && (yi >= 0.f) && (yi < Hf);
                if (valid) {
                    const int idx = (int)yi * Hl + (int)xi;
                    acc += awv * w * Vl[(size_t)idx * 256];
                }
            }
        }
    }
    acc += __shfl_xor(acc, 32);
    if (lane < 32) samp[(size_t)row * 256 + m * 32 + d] = acc;
}

// ---------------- launcher ----------------
extern "C" void kernel_launch(void* const* d_in, const int* in_sizes, int n_in,
                              void* d_out, int out_size, void* d_ws, size_t ws_size,
                              hipStream_t stream)
{
    const float* qo   = (const float*)d_in[0];
    const float* qpz  = (const float*)d_in[1];
    const float* refp = (const float*)d_in[2];
    const float* feat[4] = {(const float*)d_in[3], (const float*)d_in[5],
                            (const float*)d_in[7], (const float*)d_in[9]};
    const float* pos[4]  = {(const float*)d_in[4], (const float*)d_in[6],
                            (const float*)d_in[8], (const float*)d_in[10]};
    const float* sa_in_w  = (const float*)d_in[11];
    const float* sa_in_b  = (const float*)d_in[12];
    const float* sa_out_w = (const float*)d_in[13];
    const float* sa_out_b = (const float*)d_in[14];
    const float* n1_g = (const float*)d_in[15];
    const float* n1_b = (const float*)d_in[16];
    const float* n2_g = (const float*)d_in[17];
    const float* n2_b = (const float*)d_in[18];
    const float* n3_g = (const float*)d_in[19];
    const float* n3_b = (const float*)d_in[20];
    const float* val_w  = (const float*)d_in[21];
    const float* val_b  = (const float*)d_in[22];
    const float* off_w  = (const float*)d_in[23];
    const float* off_b  = (const float*)d_in[24];
    const float* aw_w   = (const float*)d_in[25];
    const float* aw_b   = (const float*)d_in[26];
    const float* dout_w = (const float*)d_in[27];
    const float* dout_b = (const float*)d_in[28];
    const float* ffn_w1 = (const float*)d_in[29];
    const float* ffn_b1 = (const float*)d_in[30];
    const float* ffn_w2 = (const float*)d_in[31];
    const float* ffn_b2 = (const float*)d_in[32];

    float* ws = (float*)d_ws;
    // layout (floats); h aliases QK+Vbuf+attnO; dres aliases x1; x3 aliases offb
    float* QK    = ws;                         // 14400*512 = 7,372,800
    float* Vbuf  = ws + 7372800;               // 3,686,400
    float* attnO = ws + 11059200;              // 3,686,400
    float* h     = ws;                         // 14400*1024 (alias, post-attention)
    float* x1    = ws + 14745600;              // 3,686,400
    float* dres  = x1;                         // alias (x1 dead after LN1)
    float* xln1  = ws + 18432000;              // 3,686,400
    float* offb  = ws + 22118400;              // 3,686,400
    float* x3    = offb;                       // alias (off dead after sampling)
    float* awb   = ws + 25804800;              // 14400*128 = 1,843,200
    float* samp  = ws + 27648000;              // 3,686,400
    float* xln2  = ws + 31334400;              // 3,686,400
    float* Vval  = ws + 35020800;              // 212704*256 = 54,452,224

    const dim3 blk(256);

    // 1. Q,K projections: (qo+qp) @ sa_in_w[:, :512]
    gemm_f32<true, false, false><<<dim3(8, 225), blk, 0, stream>>>(
        qo, qpz, 256, sa_in_w, 768, sa_in_b, nullptr, QK, 512, NROWS, 512, 256);
    // 2. V projection: qo @ sa_in_w[:, 512:]
    gemm_f32<false, false, false><<<dim3(4, 225), blk, 0, stream>>>(
        qo, nullptr, 256, sa_in_w + 512, 768, sa_in_b + 512, nullptr, Vbuf, 256, NROWS, 256, 256);
    // 3. self-attention (flash style)
    attn_kernel<<<dim3(28800), blk, 0, stream>>>(QK, Vbuf, attnO);
    // 4. out projection + residual(qo)
    gemm_f32<false, false, true><<<dim3(4, 225), blk, 0, stream>>>(
        attnO, nullptr, 256, sa_out_w, 256, sa_out_b, qo, x1, 256, NROWS, 256, 256);
    // 5. LN1
    ln_kernel<<<dim3(3600), blk, 0, stream>>>(x1, n1_g, n1_b, xln1, NROWS);
    // 6. sampling offsets
    gemm_f32<false, false, false><<<dim3(4, 225), blk, 0, stream>>>(
        xln1, nullptr, 256, off_w, 256, off_b, nullptr, offb, 256, NROWS, 256, 256);
    // 7. attention weights + softmax(16)
    gemm_f32<false, false, false><<<dim3(2, 225), blk, 0, stream>>>(
        xln1, nullptr, 256, aw_w, 128, aw_b, nullptr, awb, 128, NROWS, 128, 256);
    aw_softmax<<<dim3(450), blk, 0, stream>>>(awb);
    // 8. value projections per level: (feat+pos) @ val_w
    gemm_f32<true, false, false><<<dim3(4, 2500), blk, 0, stream>>>(
        feat[0], pos[0], 256, val_w, 256, val_b, nullptr, Vval, 256, 160000, 256, 256);
    gemm_f32<true, false, false><<<dim3(4, 625), blk, 0, stream>>>(
        feat[1], pos[1], 256, val_w, 256, val_b, nullptr, Vval + (size_t)160000 * 256, 256, 40000, 256, 256);
    gemm_f32<true, false, false><<<dim3(4, 157), blk, 0, stream>>>(
        feat[2], pos[2], 256, val_w, 256, val_b, nullptr, Vval + (size_t)200000 * 256, 256, 10000, 256, 256);
    gemm_f32<true, false, false><<<dim3(4, 43), blk, 0, stream>>>(
        feat[3], pos[3], 256, val_w, 256, val_b, nullptr, Vval + (size_t)210000 * 256, 256, 2704, 256, 256);
    // 9. bilinear sampling + weighted sum
    sample_kernel<<<dim3(28800), blk, 0, stream>>>(Vval, offb, awb, refp, samp);
    // 10. deform output projection + residual(xln1)
    gemm_f32<false, false, true><<<dim3(4, 225), blk, 0, stream>>>(
        samp, nullptr, 256, dout_w, 256, dout_b, xln1, dres, 256, NROWS, 256, 256);
    // 11. LN2
    ln_kernel<<<dim3(3600), blk, 0, stream>>>(dres, n2_g, n2_b, xln2, NROWS);
    // 12. FFN1 (relu)
    gemm_f32<false, true, false><<<dim3(16, 225), blk, 0, stream>>>(
        xln2, nullptr, 256, ffn_w1, 1024, ffn_b1, nullptr, h, 1024, NROWS, 1024, 256);
    // 13. FFN2 + residual(xln2)
    gemm_f32<false, false, true><<<dim3(4, 225), blk, 0, stream>>>(
        h, nullptr, 1024, ffn_w2, 256, ffn_b2, xln2, x3, 256, NROWS, 256, 1024);
    // 14. LN3 -> output
    ln_kernel<<<dim3(3600), blk, 0, stream>>>(x3, n3_g, n3_b, (float*)d_out, NROWS);
}

// Round 2
// 1284.830 us; speedup vs baseline: 3.2354x; 3.2354x over previous
//
#include <hip/hip_runtime.h>
#include <hip/hip_bf16.h>
#include <cstdint>

// ---------------- constants ----------------
#define LQ 900
#define BB 16
#define CC 256
#define MM 8
#define CV 32
#define NROWS (LQ * BB)   // 14400

typedef __attribute__((ext_vector_type(8))) short short8;
typedef __attribute__((ext_vector_type(4))) float f32x4;

__device__ __forceinline__ short f2bf(float f) {
    union { float f; unsigned u; } x; x.f = f;
    const unsigned r = x.u + 0x7fff + ((x.u >> 16) & 1);
    return (short)(r >> 16);
}

// level geometry (square levels)
__device__ __constant__ int d_HW[4]    = {100, 50, 25, 13};
__device__ __constant__ int d_baseR[4] = {0, 160000, 200000, 210000};

// ---------------- generic tiled fp32 GEMM ----------------
#define TS 64
#define KS 16

template<bool ADD_A2, bool RELU, bool RESID>
__global__ __launch_bounds__(256) void gemm_f32(
    const float* __restrict__ A, const float* __restrict__ A2, int lda,
    const float* __restrict__ Bm, int ldb, const float* __restrict__ bias,
    const float* __restrict__ resid, float* __restrict__ C, int ldc,
    int Mr, int Nc, int Kd)
{
    __shared__ float As[KS][TS];
    __shared__ float Bs[KS][TS];
    const int t  = threadIdx.x;
    const int tx = t & 15, ty = t >> 4;
    const int row0 = blockIdx.y * TS;
    const int col0 = blockIdx.x * TS;

    float acc[4][4] = {};

    const int ar = t >> 2, ak = (t & 3) * 4;
    const int bk = t >> 4, bn = (t & 15) * 4;
    const int arow  = row0 + ar;
    const int arowc = arow < Mr ? arow : (Mr - 1);

    for (int k0 = 0; k0 < Kd; k0 += KS) {
        float4 av = *reinterpret_cast<const float4*>(A + (size_t)arowc * lda + k0 + ak);
        if (ADD_A2) {
            const float4 a2 = *reinterpret_cast<const float4*>(A2 + (size_t)arowc * lda + k0 + ak);
            av.x += a2.x; av.y += a2.y; av.z += a2.z; av.w += a2.w;
        }
        As[ak + 0][ar] = av.x; As[ak + 1][ar] = av.y;
        As[ak + 2][ar] = av.z; As[ak + 3][ar] = av.w;
        *reinterpret_cast<float4*>(&Bs[bk][bn]) =
            *reinterpret_cast<const float4*>(Bm + (size_t)(k0 + bk) * ldb + col0 + bn);
        __syncthreads();

        #pragma unroll
        for (int kk = 0; kk < KS; ++kk) {
            const float4 a4 = *reinterpret_cast<const float4*>(&As[kk][ty * 4]);
            const float4 b4 = *reinterpret_cast<const float4*>(&Bs[kk][tx * 4]);
            const float aa[4] = {a4.x, a4.y, a4.z, a4.w};
            const float bb[4] = {b4.x, b4.y, b4.z, b4.w};
            #pragma unroll
            for (int i = 0; i < 4; ++i)
                #pragma unroll
                for (int j = 0; j < 4; ++j)
                    acc[i][j] += aa[i] * bb[j];
        }
        __syncthreads();
    }

    #pragma unroll
    for (int i = 0; i < 4; ++i) {
        const int r = row0 + ty * 4 + i;
        if (r >= Mr) continue;
        #pragma unroll
        for (int j = 0; j < 4; ++j) {
            const int c = col0 + tx * 4 + j;
            float v = acc[i][j] + bias[c];
            if (RESID) v += resid[(size_t)r * ldc + c];
            if (RELU)  v = fmaxf(v, 0.f);
            C[(size_t)r * ldc + c] = v;
        }
    }
}

// ---------------- MHA: bf16 MFMA flash attention ----------------
// Block = 256 threads = 4 waves; one block per (b,m, qtile of 64 rows).
// Wave w owns Q rows [q0+w*16, q0+w*16+16). KV tiled at 64.
// QK fp32: rows q*16+b, cols 0..255 Q (m*32+d), 256..511 K. Vbuf fp32 (14400,256).
__global__ __launch_bounds__(256) void attn_mfma(
    const float* __restrict__ QK, const float* __restrict__ Vbuf,
    float* __restrict__ attnO)
{
    __shared__ ushort K_lds[64][40];      // K[kv][d], padded to break banks
    __shared__ ushort Vt[32][72];         // V^T[d][kv], padded
    __shared__ ushort P_lds[4][16][72];   // per-wave P tile [qr][kv]

    const int t = threadIdx.x;
    const int w = t >> 6, lane = t & 63;
    const int q0 = blockIdx.x * 64;
    const int m = blockIdx.y & 7, b = blockIdx.y >> 3;

    const int lr = lane & 15;   // row/col within 16-tile
    const int lk = lane >> 4;   // k-group (0..3)

    // ---- load Q fragment (A-operand: lane holds Q[lr][lk*8 + j]) ----
    const int qrow = min(q0 + w * 16 + lr, LQ - 1);
    const float* qp = QK + ((size_t)qrow * BB + b) * 512 + m * 32 + lk * 8;
    short8 qf;
    {
        const float4 a = *reinterpret_cast<const float4*>(qp);
        const float4 c = *reinterpret_cast<const float4*>(qp + 4);
        qf[0] = f2bf(a.x); qf[1] = f2bf(a.y); qf[2] = f2bf(a.z); qf[3] = f2bf(a.w);
        qf[4] = f2bf(c.x); qf[5] = f2bf(c.y); qf[6] = f2bf(c.z); qf[7] = f2bf(c.w);
    }

    f32x4 oacc[2] = {f32x4{0.f,0.f,0.f,0.f}, f32x4{0.f,0.f,0.f,0.f}};
    float mrun[4] = {-1e30f, -1e30f, -1e30f, -1e30f};
    float lrun[4] = {0.f, 0.f, 0.f, 0.f};

    const float scale = 0.17677669529663687f; // 1/sqrt(32)
    const int sr = t >> 2;          // staging kv row 0..63
    const int sd = (t & 3) * 8;     // staging d offset

    for (int k0 = 0; k0 < LQ; k0 += 64) {
        // ---- stage K tile and V^T tile ----
        {
            const int kr = min(k0 + sr, LQ - 1);
            const float* kgp = QK + ((size_t)kr * BB + b) * 512 + 256 + m * 32 + sd;
            const float4 a = *reinterpret_cast<const float4*>(kgp);
            const float4 c = *reinterpret_cast<const float4*>(kgp + 4);
            short8 kv8;
            kv8[0] = f2bf(a.x); kv8[1] = f2bf(a.y); kv8[2] = f2bf(a.z); kv8[3] = f2bf(a.w);
            kv8[4] = f2bf(c.x); kv8[5] = f2bf(c.y); kv8[6] = f2bf(c.z); kv8[7] = f2bf(c.w);
            *reinterpret_cast<short8*>(&K_lds[sr][sd]) = kv8;

            const float* vgp = Vbuf + ((size_t)kr * BB + b) * 256 + m * 32 + sd;
            const float4 va = *reinterpret_cast<const float4*>(vgp);
            const float4 vc = *reinterpret_cast<const float4*>(vgp + 4);
            Vt[sd + 0][sr] = (ushort)f2bf(va.x);
            Vt[sd + 1][sr] = (ushort)f2bf(va.y);
            Vt[sd + 2][sr] = (ushort)f2bf(va.z);
            Vt[sd + 3][sr] = (ushort)f2bf(va.w);
            Vt[sd + 4][sr] = (ushort)f2bf(vc.x);
            Vt[sd + 5][sr] = (ushort)f2bf(vc.y);
            Vt[sd + 6][sr] = (ushort)f2bf(vc.z);
            Vt[sd + 7][sr] = (ushort)f2bf(vc.w);
        }
        __syncthreads();

        // ---- S = Q @ K^T (16 x 64 per wave) ----
        f32x4 sa[4];
        #pragma unroll
        for (int n = 0; n < 4; ++n) {
            const short8 kf = *reinterpret_cast<const short8*>(&K_lds[n * 16 + lr][lk * 8]);
            sa[n] = __builtin_amdgcn_mfma_f32_16x16x32_bf16(qf, kf, f32x4{0.f,0.f,0.f,0.f}, 0, 0, 0);
        }
        #pragma unroll
        for (int n = 0; n < 4; ++n)
            #pragma unroll
            for (int r = 0; r < 4; ++r)
                sa[n][r] *= scale;
        if (k0 + 64 > LQ) {   // mask tail columns
            #pragma unroll
            for (int n = 0; n < 4; ++n)
                if (k0 + n * 16 + lr >= LQ) {
                    #pragma unroll
                    for (int r = 0; r < 4; ++r) sa[n][r] = -1e30f;
                }
        }

        // ---- online softmax (rows = lk*4 + r, shared by 16 lanes of group lk) ----
        #pragma unroll
        for (int r = 0; r < 4; ++r) {
            float mx = fmaxf(fmaxf(sa[0][r], sa[1][r]), fmaxf(sa[2][r], sa[3][r]));
            #pragma unroll
            for (int o = 8; o; o >>= 1) mx = fmaxf(mx, __shfl_xor(mx, o));
            const float mnew = fmaxf(mrun[r], mx);
            const float corr = __expf(mrun[r] - mnew);
            mrun[r] = mnew;
            float psum = 0.f;
            #pragma unroll
            for (int n = 0; n < 4; ++n) {
                const float p = __expf(sa[n][r] - mnew);
                psum += p;
                P_lds[w][lk * 4 + r][n * 16 + lr] = (ushort)f2bf(p);
            }
            #pragma unroll
            for (int o = 8; o; o >>= 1) psum += __shfl_xor(psum, o);
            lrun[r] = lrun[r] * corr + psum;
            oacc[0][r] *= corr;
            oacc[1][r] *= corr;
        }

        // ---- O += P @ V ----
        #pragma unroll
        for (int kk = 0; kk < 2; ++kk) {
            const short8 pf = *reinterpret_cast<const short8*>(&P_lds[w][lr][kk * 32 + lk * 8]);
            #pragma unroll
            for (int dt = 0; dt < 2; ++dt) {
                const short8 vf = *reinterpret_cast<const short8*>(&Vt[dt * 16 + lr][kk * 32 + lk * 8]);
                oacc[dt] = __builtin_amdgcn_mfma_f32_16x16x32_bf16(pf, vf, oacc[dt], 0, 0, 0);
            }
        }
        __syncthreads();
    }

    // ---- epilogue: O / l ----
    #pragma unroll
    for (int r = 0; r < 4; ++r) {
        const int row = q0 + w * 16 + lk * 4 + r;
        if (row < LQ) {
            const float inv = 1.f / lrun[r];
            float* op = attnO + ((size_t)row * BB + b) * 256 + m * 32;
            op[lr]      = oacc[0][r] * inv;
            op[16 + lr] = oacc[1][r] * inv;
        }
    }
}

// ---------------- layernorm: one wave per row of 256 ----------------
__global__ __launch_bounds__(256) void ln_kernel(
    const float* __restrict__ X, const float* __restrict__ g,
    const float* __restrict__ bta, float* __restrict__ Y, int nrows)
{
    const int r = blockIdx.x * 4 + (threadIdx.x >> 6);
    if (r >= nrows) return;
    const int lane = threadIdx.x & 63;
    const float4 v = *reinterpret_cast<const float4*>(X + (size_t)r * 256 + lane * 4);
    float s  = v.x + v.y + v.z + v.w;
    float sq = v.x * v.x + v.y * v.y + v.z * v.z + v.w * v.w;
    #pragma unroll
    for (int o = 32; o; o >>= 1) { s += __shfl_xor(s, o); sq += __shfl_xor(sq, o); }
    const float mean = s * (1.f / 256.f);
    const float var  = sq * (1.f / 256.f) - mean * mean;
    const float rs   = rsqrtf(var + 1e-5f);
    const float4 gv = *reinterpret_cast<const float4*>(g + lane * 4);
    const float4 bv = *reinterpret_cast<const float4*>(bta + lane * 4);
    float4 o4;
    o4.x = (v.x - mean) * rs * gv.x + bv.x;
    o4.y = (v.y - mean) * rs * gv.y + bv.y;
    o4.z = (v.z - mean) * rs * gv.z + bv.z;
    o4.w = (v.w - mean) * rs * gv.w + bv.w;
    *reinterpret_cast<float4*>(Y + (size_t)r * 256 + lane * 4) = o4;
}

// ---------------- per-(row,m) softmax over L*K=16 attention weights ----------------
__global__ __launch_bounds__(256) void aw_softmax(float* __restrict__ awr)
{
    const int gid = blockIdx.x * 256 + threadIdx.x;
    if (gid >= NROWS * MM) return;
    const int row = gid >> 3, m = gid & 7;
    float* p = awr + (size_t)row * 128 + m * 16;
    float v[16], mx = -1e30f;
    #pragma unroll
    for (int i = 0; i < 16; ++i) { v[i] = p[i]; mx = fmaxf(mx, v[i]); }
    float s = 0.f;
    #pragma unroll
    for (int i = 0; i < 16; ++i) { v[i] = __expf(v[i] - mx); s += v[i]; }
    const float inv = 1.f / s;
    #pragma unroll
    for (int i = 0; i < 16; ++i) p[i] = v[i] * inv;
}

// ---------------- deformable bilinear sampling ----------------
__global__ __launch_bounds__(256) void sample_kernel(
    const float* __restrict__ Vval, const float* __restrict__ offb,
    const float* __restrict__ aw, const float* __restrict__ ref,
    float* __restrict__ samp)
{
    const int wid  = blockIdx.x * 4 + (threadIdx.x >> 6);
    const int lane = threadIdx.x & 63;
    const int q  = wid % LQ;
    const int bm = wid / LQ;
    const int m  = bm & 7, b = bm >> 3;
    const int d  = lane & 31, kh = lane >> 5;
    const int row = q * BB + b;

    const float rx = ref[row * 2 + 0];
    const float ry = ref[row * 2 + 1];

    float acc = 0.f;
    #pragma unroll
    for (int l = 0; l < 4; ++l) {
        const int   Hl = d_HW[l];
        const float Hf = (float)Hl;
        const float* Vl = Vval + ((size_t)d_baseR[l] + (size_t)b * Hl * Hl) * 256 + m * 32 + d;
        #pragma unroll
        for (int k2 = 0; k2 < 2; ++k2) {
            const int k = kh * 2 + k2;
            const float ox  = offb[(size_t)row * 256 + m * 32 + l * 8 + k * 2 + 0];
            const float oy  = offb[(size_t)row * 256 + m * 32 + l * 8 + k * 2 + 1];
            const float awv = aw[(size_t)row * 128 + m * 16 + l * 4 + k];
            const float px = rx * Hf - 0.5f + ox;
            const float py = ry * Hf - 0.5f + oy;
            const float x0 = floorf(px), y0 = floorf(py);
            #pragma unroll
            for (int c = 0; c < 4; ++c) {
                const float xi = x0 + (float)(c & 1);
                const float yi = y0 + (float)(c >> 1);
                const float w = (1.f - fabsf(px - xi)) * (1.f - fabsf(py - yi));
                const bool valid = (xi >= 0.f) && (xi < Hf) && (yi >= 0.f) && (yi < Hf);
                if (valid) {
                    const int idx = (int)yi * Hl + (int)xi;
                    acc += awv * w * Vl[(size_t)idx * 256];
                }
            }
        }
    }
    acc += __shfl_xor(acc, 32);
    if (lane < 32) samp[(size_t)row * 256 + m * 32 + d] = acc;
}

// ---------------- launcher ----------------
extern "C" void kernel_launch(void* const* d_in, const int* in_sizes, int n_in,
                              void* d_out, int out_size, void* d_ws, size_t ws_size,
                              hipStream_t stream)
{
    const float* qo   = (const float*)d_in[0];
    const float* qpz  = (const float*)d_in[1];
    const float* refp = (const float*)d_in[2];
    const float* feat[4] = {(const float*)d_in[3], (const float*)d_in[5],
                            (const float*)d_in[7], (const float*)d_in[9]};
    const float* pos[4]  = {(const float*)d_in[4], (const float*)d_in[6],
                            (const float*)d_in[8], (const float*)d_in[10]};
    const float* sa_in_w  = (const float*)d_in[11];
    const float* sa_in_b  = (const float*)d_in[12];
    const float* sa_out_w = (const float*)d_in[13];
    const float* sa_out_b = (const float*)d_in[14];
    const float* n1_g = (const float*)d_in[15];
    const float* n1_b = (const float*)d_in[16];
    const float* n2_g = (const float*)d_in[17];
    const float* n2_b = (const float*)d_in[18];
    const float* n3_g = (const float*)d_in[19];
    const float* n3_b = (const float*)d_in[20];
    const float* val_w  = (const float*)d_in[21];
    const float* val_b  = (const float*)d_in[22];
    const float* off_w  = (const float*)d_in[23];
    const float* off_b  = (const float*)d_in[24];
    const float* aw_w   = (const float*)d_in[25];
    const float* aw_b   = (const float*)d_in[26];
    const float* dout_w = (const float*)d_in[27];
    const float* dout_b = (const float*)d_in[28];
    const float* ffn_w1 = (const float*)d_in[29];
    const float* ffn_b1 = (const float*)d_in[30];
    const float* ffn_w2 = (const float*)d_in[31];
    const float* ffn_b2 = (const float*)d_in[32];

    float* ws = (float*)d_ws;
    float* QK    = ws;                         // 14400*512
    float* Vbuf  = ws + 7372800;               // 14400*256
    float* attnO = ws + 11059200;              // 14400*256
    float* h     = ws;                         // 14400*1024 (alias, post-attention)
    float* x1    = ws + 14745600;
    float* dres  = x1;
    float* xln1  = ws + 18432000;
    float* offb  = ws + 22118400;
    float* x3    = offb;
    float* awb   = ws + 25804800;
    float* samp  = ws + 27648000;
    float* xln2  = ws + 31334400;
    float* Vval  = ws + 35020800;              // 212704*256

    const dim3 blk(256);

    // 1. Q,K projections
    gemm_f32<true, false, false><<<dim3(8, 225), blk, 0, stream>>>(
        qo, qpz, 256, sa_in_w, 768, sa_in_b, nullptr, QK, 512, NROWS, 512, 256);
    // 2. V projection
    gemm_f32<false, false, false><<<dim3(4, 225), blk, 0, stream>>>(
        qo, nullptr, 256, sa_in_w + 512, 768, sa_in_b + 512, nullptr, Vbuf, 256, NROWS, 256, 256);
    // 3. self-attention (bf16 MFMA flash)
    attn_mfma<<<dim3(15, 128), blk, 0, stream>>>(QK, Vbuf, attnO);
    // 4. out projection + residual(qo)
    gemm_f32<false, false, true><<<dim3(4, 225), blk, 0, stream>>>(
        attnO, nullptr, 256, sa_out_w, 256, sa_out_b, qo, x1, 256, NROWS, 256, 256);
    // 5. LN1
    ln_kernel<<<dim3(3600), blk, 0, stream>>>(x1, n1_g, n1_b, xln1, NROWS);
    // 6. sampling offsets
    gemm_f32<false, false, false><<<dim3(4, 225), blk, 0, stream>>>(
        xln1, nullptr, 256, off_w, 256, off_b, nullptr, offb, 256, NROWS, 256, 256);
    // 7. attention weights + softmax(16)
    gemm_f32<false, false, false><<<dim3(2, 225), blk, 0, stream>>>(
        xln1, nullptr, 256, aw_w, 128, aw_b, nullptr, awb, 128, NROWS, 128, 256);
    aw_softmax<<<dim3(450), blk, 0, stream>>>(awb);
    // 8. value projections per level
    gemm_f32<true, false, false><<<dim3(4, 2500), blk, 0, stream>>>(
        feat[0], pos[0], 256, val_w, 256, val_b, nullptr, Vval, 256, 160000, 256, 256);
    gemm_f32<true, false, false><<<dim3(4, 625), blk, 0, stream>>>(
        feat[1], pos[1], 256, val_w, 256, val_b, nullptr, Vval + (size_t)160000 * 256, 256, 40000, 256, 256);
    gemm_f32<true, false, false><<<dim3(4, 157), blk, 0, stream>>>(
        feat[2], pos[2], 256, val_w, 256, val_b, nullptr, Vval + (size_t)200000 * 256, 256, 10000, 256, 256);
    gemm_f32<true, false, false><<<dim3(4, 43), blk, 0, stream>>>(
        feat[3], pos[3], 256, val_w, 256, val_b, nullptr, Vval + (size_t)210000 * 256, 256, 2704, 256, 256);
    // 9. bilinear sampling
    sample_kernel<<<dim3(28800), blk, 0, stream>>>(Vval, offb, awb, refp, samp);
    // 10. deform output projection + residual(xln1)
    gemm_f32<false, false, true><<<dim3(4, 225), blk, 0, stream>>>(
        samp, nullptr, 256, dout_w, 256, dout_b, xln1, dres, 256, NROWS, 256, 256);
    // 11. LN2
    ln_kernel<<<dim3(3600), blk, 0, stream>>>(dres, n2_g, n2_b, xln2, NROWS);
    // 12. FFN1 (relu)
    gemm_f32<false, true, false><<<dim3(16, 225), blk, 0, stream>>>(
        xln2, nullptr, 256, ffn_w1, 1024, ffn_b1, nullptr, h, 1024, NROWS, 1024, 256);
    // 13. FFN2 + residual(xln2)
    gemm_f32<false, false, true><<<dim3(4, 225), blk, 0, stream>>>(
        h, nullptr, 1024, ffn_w2, 256, ffn_b2, xln2, x3, 256, NROWS, 256, 1024);
    // 14. LN3 -> output
    ln_kernel<<<dim3(3600), blk, 0, stream>>>(x3, n3_g, n3_b, (float*)d_out, NROWS);
}

// Round 4
// 1048.331 us; speedup vs baseline: 3.9653x; 1.2256x over previous
//
#include <hip/hip_runtime.h>
#include <hip/hip_bf16.h>
#include <cstdint>

// ---------------- constants ----------------
#define LQ 900
#define BB 16
#define CC 256
#define MM 8
#define CV 32
#define NROWS (LQ * BB)   // 14400

typedef __attribute__((ext_vector_type(8))) short short8;
typedef __attribute__((ext_vector_type(4))) float f32x4;

__device__ __forceinline__ short f2bf(float f) {
    union { float f; unsigned u; } x; x.f = f;
    const unsigned r = x.u + 0x7fff + ((x.u >> 16) & 1);
    return (short)(r >> 16);
}
__device__ __forceinline__ float bf2f(ushort u) {
    union { unsigned u; float f; } c; c.u = ((unsigned)u) << 16; return c.f;
}

// level geometry (square levels)
__device__ __constant__ int d_HW[4]    = {100, 50, 25, 13};
__device__ __constant__ int d_baseR[4] = {0, 160000, 200000, 210000};

// ---------------- weight transpose+convert: W(K,N) f32 -> Wt(N,K) bf16 ----------------
__global__ __launch_bounds__(256) void conv_w_T(
    const float* __restrict__ W, ushort* __restrict__ Wt, int K, int N)
{
    __shared__ float tl[32][33];
    const int t = threadIdx.x;
    const int tx = t & 31, ty = t >> 5;
    const int n0 = blockIdx.x * 32, k0 = blockIdx.y * 32;
    #pragma unroll
    for (int p = 0; p < 4; ++p)
        tl[ty + 8 * p][tx] = W[(size_t)(k0 + ty + 8 * p) * N + n0 + tx];
    __syncthreads();
    #pragma unroll
    for (int p = 0; p < 4; ++p)
        Wt[(size_t)(n0 + ty + 8 * p) * K + k0 + tx] = (ushort)f2bf(tl[tx][ty + 8 * p]);
}

// ---------------- generic tiled fp32 GEMM (proven R2 engine) ----------------
#define TS 64
#define KS 16

template<bool ADD_A2, bool RELU, bool RESID>
__global__ __launch_bounds__(256) void gemm_f32(
    const float* __restrict__ A, const float* __restrict__ A2, int lda,
    const float* __restrict__ Bm, int ldb, const float* __restrict__ bias,
    const float* __restrict__ resid, float* __restrict__ C, int ldc,
    int Mr, int Nc, int Kd)
{
    __shared__ float As[KS][TS];
    __shared__ float Bs[KS][TS];
    const int t  = threadIdx.x;
    const int tx = t & 15, ty = t >> 4;
    const int row0 = blockIdx.y * TS;
    const int col0 = blockIdx.x * TS;

    float acc[4][4] = {};

    const int ar = t >> 2, ak = (t & 3) * 4;
    const int bk = t >> 4, bn = (t & 15) * 4;
    const int arow  = row0 + ar;
    const int arowc = arow < Mr ? arow : (Mr - 1);

    for (int k0 = 0; k0 < Kd; k0 += KS) {
        float4 av = *reinterpret_cast<const float4*>(A + (size_t)arowc * lda + k0 + ak);
        if (ADD_A2) {
            const float4 a2 = *reinterpret_cast<const float4*>(A2 + (size_t)arowc * lda + k0 + ak);
            av.x += a2.x; av.y += a2.y; av.z += a2.z; av.w += a2.w;
        }
        As[ak + 0][ar] = av.x; As[ak + 1][ar] = av.y;
        As[ak + 2][ar] = av.z; As[ak + 3][ar] = av.w;
        *reinterpret_cast<float4*>(&Bs[bk][bn]) =
            *reinterpret_cast<const float4*>(Bm + (size_t)(k0 + bk) * ldb + col0 + bn);
        __syncthreads();

        #pragma unroll
        for (int kk = 0; kk < KS; ++kk) {
            const float4 a4 = *reinterpret_cast<const float4*>(&As[kk][ty * 4]);
            const float4 b4 = *reinterpret_cast<const float4*>(&Bs[kk][tx * 4]);
            const float aa[4] = {a4.x, a4.y, a4.z, a4.w};
            const float bb[4] = {b4.x, b4.y, b4.z, b4.w};
            #pragma unroll
            for (int i = 0; i < 4; ++i)
                #pragma unroll
                for (int j = 0; j < 4; ++j)
                    acc[i][j] += aa[i] * bb[j];
        }
        __syncthreads();
    }

    #pragma unroll
    for (int i = 0; i < 4; ++i) {
        const int r = row0 + ty * 4 + i;
        if (r >= Mr) continue;
        #pragma unroll
        for (int j = 0; j < 4; ++j) {
            const int c = col0 + tx * 4 + j;
            float v = acc[i][j] + bias[c];
            if (RESID) v += resid[(size_t)r * ldc + c];
            if (RELU)  v = fmaxf(v, 0.f);
            C[(size_t)r * ldc + c] = v;
        }
    }
}

// ---------------- bf16 MFMA GEMM (kept for QKV / out-proj / val-proj) ----------------
template<bool A_BF16, bool ADD_A2, bool RELU, bool RESID, bool OUT_BF16>
__global__ __launch_bounds__(256) void gemm_bf16(
    const void* __restrict__ Ap, const float* __restrict__ A2, int lda,
    const ushort* __restrict__ Bt, const float* __restrict__ bias,
    const float* __restrict__ resid, void* __restrict__ Cp, int ldc,
    int Mr, int Kd)
{
    __shared__ ushort As[128 * 64];
    __shared__ ushort Bs[128 * 64];
    const int t = threadIdx.x;
    const int lane = t & 63;
    const int w = t >> 6;
    const int wr = w >> 1, wc = w & 1;
    const int lr = lane & 15, lk = lane >> 4;
    const int row0 = blockIdx.y * 128;
    const int col0 = blockIdx.x * 128;

    f32x4 acc[4][4] = {};

    const int srow = t >> 4;          // 0..15
    const int skq  = (t & 15) * 4;    // k-offset in elements
    const int sg   = (t & 15) >> 1;   // 16B granule 0..7
    const int srem = (t & 1) * 8;     // byte remainder within granule

    const float*  Af = (const float*)Ap;
    const ushort* Ah = (const ushort*)Ap;

    for (int k0 = 0; k0 < Kd; k0 += 64) {
        #pragma unroll
        for (int p = 0; p < 8; ++p) {
            const int r  = p * 16 + srow;
            const int gr = min(row0 + r, Mr - 1);
            short4 a4;
            if (A_BF16) {
                a4 = *reinterpret_cast<const short4*>(Ah + (size_t)gr * lda + k0 + skq);
            } else {
                float4 av = *reinterpret_cast<const float4*>(Af + (size_t)gr * lda + k0 + skq);
                if (ADD_A2) {
                    const float4 b4 = *reinterpret_cast<const float4*>(A2 + (size_t)gr * lda + k0 + skq);
                    av.x += b4.x; av.y += b4.y; av.z += b4.z; av.w += b4.w;
                }
                a4.x = f2bf(av.x); a4.y = f2bf(av.y); a4.z = f2bf(av.z); a4.w = f2bf(av.w);
            }
            const int byteA = r * 128 + ((sg ^ (r & 7)) << 4) + srem;
            *reinterpret_cast<short4*>((char*)As + byteA) = a4;
            const short4 b4v = *reinterpret_cast<const short4*>(Bt + (size_t)(col0 + r) * Kd + k0 + skq);
            *reinterpret_cast<short4*>((char*)Bs + byteA) = b4v;
        }
        __syncthreads();

        #pragma unroll
        for (int kk = 0; kk < 2; ++kk) {
            short8 af[4], bfr[4];
            #pragma unroll
            for (int i = 0; i < 4; ++i) {
                const int r = wr * 64 + i * 16 + lr;
                const int byte = r * 128 + (((kk * 4 + lk) ^ (r & 7)) << 4);
                af[i] = *reinterpret_cast<const short8*>((char*)As + byte);
            }
            #pragma unroll
            for (int j = 0; j < 4; ++j) {
                const int r = wc * 64 + j * 16 + lr;
                const int byte = r * 128 + (((kk * 4 + lk) ^ (r & 7)) << 4);
                bfr[j] = *reinterpret_cast<const short8*>((char*)Bs + byte);
            }
            #pragma unroll
            for (int i = 0; i < 4; ++i)
                #pragma unroll
                for (int j = 0; j < 4; ++j)
                    acc[i][j] = __builtin_amdgcn_mfma_f32_16x16x32_bf16(af[i], bfr[j], acc[i][j], 0, 0, 0);
        }
        __syncthreads();
    }

    float*  Cf = (float*)Cp;
    ushort* Cb = (ushort*)Cp;
    #pragma unroll
    for (int j = 0; j < 4; ++j) {
        const int col = col0 + wc * 64 + j * 16 + lr;
        const float bcol = bias[col];
        #pragma unroll
        for (int i = 0; i < 4; ++i) {
            const int rbase = row0 + wr * 64 + i * 16 + lk * 4;
            #pragma unroll
            for (int reg = 0; reg < 4; ++reg) {
                const int r = rbase + reg;
                if (r < Mr) {
                    float v = acc[i][j][reg] + bcol;
                    if (RESID) v += resid[(size_t)r * ldc + col];
                    if (RELU)  v = fmaxf(v, 0.f);
                    if (OUT_BF16) Cb[(size_t)r * ldc + col] = (ushort)f2bf(v);
                    else          Cf[(size_t)r * ldc + col] = v;
                }
            }
        }
    }
}

// ---------------- MHA: bf16 MFMA flash attention (bf16 inputs) ----------------
__global__ __launch_bounds__(256) void attn_mfma(
    const ushort* __restrict__ QKbf, const ushort* __restrict__ Vbf,
    ushort* __restrict__ attnO)
{
    __shared__ ushort K_lds[64][40];
    __shared__ ushort Vt[32][72];
    __shared__ ushort P_lds[4][16][72];

    const int t = threadIdx.x;
    const int w = t >> 6, lane = t & 63;
    const int q0 = blockIdx.x * 64;
    const int m = blockIdx.y & 7, b = blockIdx.y >> 3;

    const int lr = lane & 15;
    const int lk = lane >> 4;

    const int qrow = min(q0 + w * 16 + lr, LQ - 1);
    const short8 qf = *reinterpret_cast<const short8*>(
        QKbf + ((size_t)qrow * BB + b) * 512 + m * 32 + lk * 8);

    f32x4 oacc[2] = {f32x4{0.f,0.f,0.f,0.f}, f32x4{0.f,0.f,0.f,0.f}};
    float mrun[4] = {-1e30f, -1e30f, -1e30f, -1e30f};
    float lrun[4] = {0.f, 0.f, 0.f, 0.f};

    const float scale = 0.17677669529663687f; // 1/sqrt(32)
    const int sr = t >> 2;
    const int sd = (t & 3) * 8;

    for (int k0 = 0; k0 < LQ; k0 += 64) {
        {
            const int kr = min(k0 + sr, LQ - 1);
            *reinterpret_cast<short8*>(&K_lds[sr][sd]) =
                *reinterpret_cast<const short8*>(QKbf + ((size_t)kr * BB + b) * 512 + 256 + m * 32 + sd);
            const short8 v8 = *reinterpret_cast<const short8*>(
                Vbf + ((size_t)kr * BB + b) * 256 + m * 32 + sd);
            #pragma unroll
            for (int j = 0; j < 8; ++j) Vt[sd + j][sr] = (ushort)v8[j];
        }
        __syncthreads();

        f32x4 sa[4];
        #pragma unroll
        for (int n = 0; n < 4; ++n) {
            const short8 kf = *reinterpret_cast<const short8*>(&K_lds[n * 16 + lr][lk * 8]);
            sa[n] = __builtin_amdgcn_mfma_f32_16x16x32_bf16(qf, kf, f32x4{0.f,0.f,0.f,0.f}, 0, 0, 0);
        }
        #pragma unroll
        for (int n = 0; n < 4; ++n)
            #pragma unroll
            for (int r = 0; r < 4; ++r)
                sa[n][r] *= scale;
        if (k0 + 64 > LQ) {
            #pragma unroll
            for (int n = 0; n < 4; ++n)
                if (k0 + n * 16 + lr >= LQ) {
                    #pragma unroll
                    for (int r = 0; r < 4; ++r) sa[n][r] = -1e30f;
                }
        }

        #pragma unroll
        for (int r = 0; r < 4; ++r) {
            float mx = fmaxf(fmaxf(sa[0][r], sa[1][r]), fmaxf(sa[2][r], sa[3][r]));
            #pragma unroll
            for (int o = 8; o; o >>= 1) mx = fmaxf(mx, __shfl_xor(mx, o));
            const float mnew = fmaxf(mrun[r], mx);
            const float corr = __expf(mrun[r] - mnew);
            mrun[r] = mnew;
            float psum = 0.f;
            #pragma unroll
            for (int n = 0; n < 4; ++n) {
                const float p = __expf(sa[n][r] - mnew);
                psum += p;
                P_lds[w][lk * 4 + r][n * 16 + lr] = (ushort)f2bf(p);
            }
            #pragma unroll
            for (int o = 8; o; o >>= 1) psum += __shfl_xor(psum, o);
            lrun[r] = lrun[r] * corr + psum;
            oacc[0][r] *= corr;
            oacc[1][r] *= corr;
        }

        #pragma unroll
        for (int kk = 0; kk < 2; ++kk) {
            const short8 pf = *reinterpret_cast<const short8*>(&P_lds[w][lr][kk * 32 + lk * 8]);
            #pragma unroll
            for (int dt = 0; dt < 2; ++dt) {
                const short8 vf = *reinterpret_cast<const short8*>(&Vt[dt * 16 + lr][kk * 32 + lk * 8]);
                oacc[dt] = __builtin_amdgcn_mfma_f32_16x16x32_bf16(pf, vf, oacc[dt], 0, 0, 0);
            }
        }
        __syncthreads();
    }

    #pragma unroll
    for (int r = 0; r < 4; ++r) {
        const int row = q0 + w * 16 + lk * 4 + r;
        if (row < LQ) {
            const float inv = 1.f / lrun[r];
            ushort* op = attnO + ((size_t)row * BB + b) * 256 + m * 32;
            op[lr]      = (ushort)f2bf(oacc[0][r] * inv);
            op[16 + lr] = (ushort)f2bf(oacc[1][r] * inv);
        }
    }
}

// ---------------- layernorm: one wave per row of 256 ----------------
__global__ __launch_bounds__(256) void ln_kernel(
    const float* __restrict__ X, const float* __restrict__ g,
    const float* __restrict__ bta, float* __restrict__ Y, int nrows)
{
    const int r = blockIdx.x * 4 + (threadIdx.x >> 6);
    if (r >= nrows) return;
    const int lane = threadIdx.x & 63;
    const float4 v = *reinterpret_cast<const float4*>(X + (size_t)r * 256 + lane * 4);
    float s  = v.x + v.y + v.z + v.w;
    float sq = v.x * v.x + v.y * v.y + v.z * v.z + v.w * v.w;
    #pragma unroll
    for (int o = 32; o; o >>= 1) { s += __shfl_xor(s, o); sq += __shfl_xor(sq, o); }
    const float mean = s * (1.f / 256.f);
    const float var  = sq * (1.f / 256.f) - mean * mean;
    const float rs   = rsqrtf(var + 1e-5f);
    const float4 gv = *reinterpret_cast<const float4*>(g + lane * 4);
    const float4 bv = *reinterpret_cast<const float4*>(bta + lane * 4);
    float4 o4;
    o4.x = (v.x - mean) * rs * gv.x + bv.x;
    o4.y = (v.y - mean) * rs * gv.y + bv.y;
    o4.z = (v.z - mean) * rs * gv.z + bv.z;
    o4.w = (v.w - mean) * rs * gv.w + bv.w;
    *reinterpret_cast<float4*>(Y + (size_t)r * 256 + lane * 4) = o4;
}

// ---------------- per-(row,m) softmax over L*K=16 attention weights ----------------
__global__ __launch_bounds__(256) void aw_softmax(float* __restrict__ awr)
{
    const int gid = blockIdx.x * 256 + threadIdx.x;
    if (gid >= NROWS * MM) return;
    const int row = gid >> 3, m = gid & 7;
    float* p = awr + (size_t)row * 128 + m * 16;
    float v[16], mx = -1e30f;
    #pragma unroll
    for (int i = 0; i < 16; ++i) { v[i] = p[i]; mx = fmaxf(mx, v[i]); }
    float s = 0.f;
    #pragma unroll
    for (int i = 0; i < 16; ++i) { v[i] = __expf(v[i] - mx); s += v[i]; }
    const float inv = 1.f / s;
    #pragma unroll
    for (int i = 0; i < 16; ++i) p[i] = v[i] * inv;
}

// ---------------- deformable bilinear sampling (bf16 values, f32 out) ----------------
__global__ __launch_bounds__(256) void sample_kernel(
    const ushort* __restrict__ Vval, const float* __restrict__ offb,
    const float* __restrict__ aw, const float* __restrict__ ref,
    float* __restrict__ samp)
{
    const int wid  = blockIdx.x * 4 + (threadIdx.x >> 6);
    const int lane = threadIdx.x & 63;
    const int q  = wid % LQ;
    const int bm = wid / LQ;
    const int m  = bm & 7, b = bm >> 3;
    const int d  = lane & 31, kh = lane >> 5;
    const int row = q * BB + b;

    const float rx = ref[row * 2 + 0];
    const float ry = ref[row * 2 + 1];

    float acc = 0.f;
    #pragma unroll
    for (int l = 0; l < 4; ++l) {
        const int   Hl = d_HW[l];
        const float Hf = (float)Hl;
        const ushort* Vl = Vval + ((size_t)d_baseR[l] + (size_t)b * Hl * Hl) * 256 + m * 32 + d;
        #pragma unroll
        for (int k2 = 0; k2 < 2; ++k2) {
            const int k = kh * 2 + k2;
            const float ox  = offb[(size_t)row * 256 + m * 32 + l * 8 + k * 2 + 0];
            const float oy  = offb[(size_t)row * 256 + m * 32 + l * 8 + k * 2 + 1];
            const float awv = aw[(size_t)row * 128 + m * 16 + l * 4 + k];
            const float px = rx * Hf - 0.5f + ox;
            const float py = ry * Hf - 0.5f + oy;
            const float x0 = floorf(px), y0 = floorf(py);
            #pragma unroll
            for (int c = 0; c < 4; ++c) {
                const float xi = x0 + (float)(c & 1);
                const float yi = y0 + (float)(c >> 1);
                const float wv = (1.f - fabsf(px - xi)) * (1.f - fabsf(py - yi));
                const bool valid = (xi >= 0.f) && (xi < Hf) && (yi >= 0.f) && (yi < Hf);
                if (valid) {
                    const int idx = (int)yi * Hl + (int)xi;
                    acc += awv * wv * bf2f(Vl[(size_t)idx * 256]);
                }
            }
        }
    }
    acc += __shfl_xor(acc, 32);
    if (lane < 32) samp[(size_t)row * 256 + m * 32 + d] = acc;
}

// ---------------- launcher ----------------
extern "C" void kernel_launch(void* const* d_in, const int* in_sizes, int n_in,
                              void* d_out, int out_size, void* d_ws, size_t ws_size,
                              hipStream_t stream)
{
    const float* qo   = (const float*)d_in[0];
    const float* qpz  = (const float*)d_in[1];
    const float* refp = (const float*)d_in[2];
    const float* feat[4] = {(const float*)d_in[3], (const float*)d_in[5],
                            (const float*)d_in[7], (const float*)d_in[9]};
    const float* pos[4]  = {(const float*)d_in[4], (const float*)d_in[6],
                            (const float*)d_in[8], (const float*)d_in[10]};
    const float* sa_in_w  = (const float*)d_in[11];
    const float* sa_in_b  = (const float*)d_in[12];
    const float* sa_out_w = (const float*)d_in[13];
    const float* sa_out_b = (const float*)d_in[14];
    const float* n1_g = (const float*)d_in[15];
    const float* n1_b = (const float*)d_in[16];
    const float* n2_g = (const float*)d_in[17];
    const float* n2_b = (const float*)d_in[18];
    const float* n3_g = (const float*)d_in[19];
    const float* n3_b = (const float*)d_in[20];
    const float* val_w  = (const float*)d_in[21];
    const float* val_b  = (const float*)d_in[22];
    const float* off_w  = (const float*)d_in[23];
    const float* off_b  = (const float*)d_in[24];
    const float* aw_w   = (const float*)d_in[25];
    const float* aw_b   = (const float*)d_in[26];
    const float* dout_w = (const float*)d_in[27];
    const float* dout_b = (const float*)d_in[28];
    const float* ffn_w1 = (const float*)d_in[29];
    const float* ffn_b1 = (const float*)d_in[30];
    const float* ffn_w2 = (const float*)d_in[31];
    const float* ffn_b2 = (const float*)d_in[32];

    char* ws = (char*)d_ws;
    // bf16 buffers
    ushort* QKbf   = (ushort*)(ws + 0);             // 14400*512*2 = 14,745,600
    ushort* Vbf    = (ushort*)(ws + 14745600);      // 7,372,800
    ushort* attnO  = (ushort*)(ws + 22118400);      // 7,372,800
    ushort* Vval   = (ushort*)(ws + 29491200);      // 212704*256*2 = 108,904,448
    ushort* WsaInT = (ushort*)(ws + 138395648);     // 768*256*2 = 393,216
    ushort* WsaOutT= (ushort*)(ws + 138788864);     // 131,072
    ushort* WvalT  = (ushort*)(ws + 138919936);     // 131,072
    // f32 buffers
    float* x1   = (float*)(ws + 139051008);         // 14,745,600
    float* dres = x1;
    float* xln1 = (float*)(ws + 153796608);         // 14,745,600
    float* offb = (float*)(ws + 168542208);         // 14,745,600
    float* x3   = offb;                             // alias (offb dead after sampling)
    float* awb  = (float*)(ws + 183287808);         // 14400*128*4 = 7,372,800
    float* samp = (float*)(ws + 190660608);         // 14,745,600
    float* xln2 = (float*)(ws + 205406208);         // 14,745,600
    float* h    = (float*)(ws + 220151808);         // 14400*1024*4 = 58,982,400

    const dim3 blk(256);
    const int GM = (NROWS + 127) / 128;             // 113

    // 0. weight transpose+convert to bf16 (N,K) — only for bf16 GEMMs
    conv_w_T<<<dim3(24, 8), blk, 0, stream>>>(sa_in_w, WsaInT, 256, 768);
    conv_w_T<<<dim3(8, 8), blk, 0, stream>>>(sa_out_w, WsaOutT, 256, 256);
    conv_w_T<<<dim3(8, 8), blk, 0, stream>>>(val_w, WvalT, 256, 256);

    // 1. Q,K projections -> QKbf (bf16)
    gemm_bf16<false, true, false, false, true><<<dim3(4, GM), blk, 0, stream>>>(
        qo, qpz, 256, WsaInT, sa_in_b, nullptr, QKbf, 512, NROWS, 256);
    // 2. V projection -> Vbf
    gemm_bf16<false, false, false, false, true><<<dim3(2, GM), blk, 0, stream>>>(
        qo, nullptr, 256, WsaInT + 512 * 256, sa_in_b + 512, nullptr, Vbf, 256, NROWS, 256);
    // 3. self-attention
    attn_mfma<<<dim3(15, 128), blk, 0, stream>>>(QKbf, Vbf, attnO);
    // 4. out projection + residual(qo) -> x1 f32
    gemm_bf16<true, false, false, true, false><<<dim3(2, GM), blk, 0, stream>>>(
        attnO, nullptr, 256, WsaOutT, sa_out_b, qo, x1, 256, NROWS, 256);
    // 5. LN1
    ln_kernel<<<dim3(3600), blk, 0, stream>>>(x1, n1_g, n1_b, xln1, NROWS);
    // 6. sampling offsets -> offb f32  [f32 engine — bisection]
    gemm_f32<false, false, false><<<dim3(4, 225), blk, 0, stream>>>(
        xln1, nullptr, 256, off_w, 256, off_b, nullptr, offb, 256, NROWS, 256, 256);
    // 7. attention weights -> awb f32, softmax(16)  [f32 engine — bisection]
    gemm_f32<false, false, false><<<dim3(2, 225), blk, 0, stream>>>(
        xln1, nullptr, 256, aw_w, 128, aw_b, nullptr, awb, 128, NROWS, 128, 256);
    aw_softmax<<<dim3(450), blk, 0, stream>>>(awb);
    // 8. value projections per level -> Vval bf16 [kept bf16 — big win]
    gemm_bf16<false, true, false, false, true><<<dim3(2, 1250), blk, 0, stream>>>(
        feat[0], pos[0], 256, WvalT, val_b, nullptr, Vval, 256, 160000, 256);
    gemm_bf16<false, true, false, false, true><<<dim3(2, 313), blk, 0, stream>>>(
        feat[1], pos[1], 256, WvalT, val_b, nullptr, Vval + (size_t)160000 * 256, 256, 40000, 256);
    gemm_bf16<false, true, false, false, true><<<dim3(2, 79), blk, 0, stream>>>(
        feat[2], pos[2], 256, WvalT, val_b, nullptr, Vval + (size_t)200000 * 256, 256, 10000, 256);
    gemm_bf16<false, true, false, false, true><<<dim3(2, 22), blk, 0, stream>>>(
        feat[3], pos[3], 256, WvalT, val_b, nullptr, Vval + (size_t)210000 * 256, 256, 2704, 256);
    // 9. bilinear sampling -> samp f32
    sample_kernel<<<dim3(28800), blk, 0, stream>>>(Vval, offb, awb, refp, samp);
    // 10. deform output projection + residual(xln1) -> dres f32 [f32 engine — bisection]
    gemm_f32<false, false, true><<<dim3(4, 225), blk, 0, stream>>>(
        samp, nullptr, 256, dout_w, 256, dout_b, xln1, dres, 256, NROWS, 256, 256);
    // 11. LN2
    ln_kernel<<<dim3(3600), blk, 0, stream>>>(dres, n2_g, n2_b, xln2, NROWS);
    // 12. FFN1 (relu) -> h f32 [f32 engine — bisection]
    gemm_f32<false, true, false><<<dim3(16, 225), blk, 0, stream>>>(
        xln2, nullptr, 256, ffn_w1, 1024, ffn_b1, nullptr, h, 1024, NROWS, 1024, 256);
    // 13. FFN2 + residual(xln2) -> x3 f32 [f32 engine — bisection]
    gemm_f32<false, false, true><<<dim3(4, 225), blk, 0, stream>>>(
        h, nullptr, 1024, ffn_w2, 256, ffn_b2, xln2, x3, 256, NROWS, 256, 1024);
    // 14. LN3 -> output
    ln_kernel<<<dim3(3600), blk, 0, stream>>>(x3, n3_g, n3_b, (float*)d_out, NROWS);
}

// Round 5
// 783.017 us; speedup vs baseline: 5.3089x; 1.3388x over previous
//
#include <hip/hip_runtime.h>
#include <hip/hip_bf16.h>
#include <cstdint>

// ---------------- constants ----------------
#define LQ 900
#define BB 16
#define CC 256
#define MM 8
#define CV 32
#define NROWS (LQ * BB)   // 14400

typedef __attribute__((ext_vector_type(8))) short short8;
typedef __attribute__((ext_vector_type(4))) float f32x4;

__device__ __forceinline__ short f2bf(float f) {
    union { float f; unsigned u; } x; x.f = f;
    const unsigned r = x.u + 0x7fff + ((x.u >> 16) & 1);
    return (short)(r >> 16);
}
__device__ __forceinline__ float bf2f(ushort u) {
    union { unsigned u; float f; } c; c.u = ((unsigned)u) << 16; return c.f;
}

// level geometry (square levels)
__device__ __constant__ int d_HW[4]    = {100, 50, 25, 13};
__device__ __constant__ int d_baseR[4] = {0, 160000, 200000, 210000};

// ---------------- weight transpose+convert: W(K,N) f32 -> Wt(N,K) bf16 ----------------
__global__ __launch_bounds__(256) void conv_w_T(
    const float* __restrict__ W, ushort* __restrict__ Wt, int K, int N)
{
    __shared__ float tl[32][33];
    const int t = threadIdx.x;
    const int tx = t & 31, ty = t >> 5;
    const int n0 = blockIdx.x * 32, k0 = blockIdx.y * 32;
    #pragma unroll
    for (int p = 0; p < 4; ++p)
        tl[ty + 8 * p][tx] = W[(size_t)(k0 + ty + 8 * p) * N + n0 + tx];
    __syncthreads();
    #pragma unroll
    for (int p = 0; p < 4; ++p)
        Wt[(size_t)(n0 + ty + 8 * p) * K + k0 + tx] = (ushort)f2bf(tl[tx][ty + 8 * p]);
}

// ---------------- generic tiled fp32 GEMM (proven engine, kept for off/aw) ----------------
#define TS 64
#define KS 16

template<bool ADD_A2, bool RELU, bool RESID>
__global__ __launch_bounds__(256) void gemm_f32(
    const float* __restrict__ A, const float* __restrict__ A2, int lda,
    const float* __restrict__ Bm, int ldb, const float* __restrict__ bias,
    const float* __restrict__ resid, float* __restrict__ C, int ldc,
    int Mr, int Nc, int Kd)
{
    __shared__ float As[KS][TS];
    __shared__ float Bs[KS][TS];
    const int t  = threadIdx.x;
    const int tx = t & 15, ty = t >> 4;
    const int row0 = blockIdx.y * TS;
    const int col0 = blockIdx.x * TS;

    float acc[4][4] = {};

    const int ar = t >> 2, ak = (t & 3) * 4;
    const int bk = t >> 4, bn = (t & 15) * 4;
    const int arow  = row0 + ar;
    const int arowc = arow < Mr ? arow : (Mr - 1);

    for (int k0 = 0; k0 < Kd; k0 += KS) {
        float4 av = *reinterpret_cast<const float4*>(A + (size_t)arowc * lda + k0 + ak);
        if (ADD_A2) {
            const float4 a2 = *reinterpret_cast<const float4*>(A2 + (size_t)arowc * lda + k0 + ak);
            av.x += a2.x; av.y += a2.y; av.z += a2.z; av.w += a2.w;
        }
        As[ak + 0][ar] = av.x; As[ak + 1][ar] = av.y;
        As[ak + 2][ar] = av.z; As[ak + 3][ar] = av.w;
        *reinterpret_cast<float4*>(&Bs[bk][bn]) =
            *reinterpret_cast<const float4*>(Bm + (size_t)(k0 + bk) * ldb + col0 + bn);
        __syncthreads();

        #pragma unroll
        for (int kk = 0; kk < KS; ++kk) {
            const float4 a4 = *reinterpret_cast<const float4*>(&As[kk][ty * 4]);
            const float4 b4 = *reinterpret_cast<const float4*>(&Bs[kk][tx * 4]);
            const float aa[4] = {a4.x, a4.y, a4.z, a4.w};
            const float bb[4] = {b4.x, b4.y, b4.z, b4.w};
            #pragma unroll
            for (int i = 0; i < 4; ++i)
                #pragma unroll
                for (int j = 0; j < 4; ++j)
                    acc[i][j] += aa[i] * bb[j];
        }
        __syncthreads();
    }

    #pragma unroll
    for (int i = 0; i < 4; ++i) {
        const int r = row0 + ty * 4 + i;
        if (r >= Mr) continue;
        #pragma unroll
        for (int j = 0; j < 4; ++j) {
            const int c = col0 + tx * 4 + j;
            float v = acc[i][j] + bias[c];
            if (RESID) v += resid[(size_t)r * ldc + c];
            if (RELU)  v = fmaxf(v, 0.f);
            C[(size_t)r * ldc + c] = v;
        }
    }
}

// ---------------- bf16 MFMA GEMM ----------------
template<bool A_BF16, bool ADD_A2, bool RELU, bool RESID, bool OUT_BF16>
__global__ __launch_bounds__(256) void gemm_bf16(
    const void* __restrict__ Ap, const float* __restrict__ A2, int lda,
    const ushort* __restrict__ Bt, const float* __restrict__ bias,
    const float* __restrict__ resid, void* __restrict__ Cp, int ldc,
    int Mr, int Kd)
{
    __shared__ ushort As[128 * 64];
    __shared__ ushort Bs[128 * 64];
    const int t = threadIdx.x;
    const int lane = t & 63;
    const int w = t >> 6;
    const int wr = w >> 1, wc = w & 1;
    const int lr = lane & 15, lk = lane >> 4;
    const int row0 = blockIdx.y * 128;
    const int col0 = blockIdx.x * 128;

    f32x4 acc[4][4] = {};

    const int srow = t >> 4;          // 0..15
    const int skq  = (t & 15) * 4;    // k-offset in elements
    const int sg   = (t & 15) >> 1;   // 16B granule 0..7
    const int srem = (t & 1) * 8;     // byte remainder within granule

    const float*  Af = (const float*)Ap;
    const ushort* Ah = (const ushort*)Ap;

    for (int k0 = 0; k0 < Kd; k0 += 64) {
        #pragma unroll
        for (int p = 0; p < 8; ++p) {
            const int r  = p * 16 + srow;
            const int gr = min(row0 + r, Mr - 1);
            short4 a4;
            if (A_BF16) {
                a4 = *reinterpret_cast<const short4*>(Ah + (size_t)gr * lda + k0 + skq);
            } else {
                float4 av = *reinterpret_cast<const float4*>(Af + (size_t)gr * lda + k0 + skq);
                if (ADD_A2) {
                    const float4 b4 = *reinterpret_cast<const float4*>(A2 + (size_t)gr * lda + k0 + skq);
                    av.x += b4.x; av.y += b4.y; av.z += b4.z; av.w += b4.w;
                }
                a4.x = f2bf(av.x); a4.y = f2bf(av.y); a4.z = f2bf(av.z); a4.w = f2bf(av.w);
            }
            const int byteA = r * 128 + ((sg ^ (r & 7)) << 4) + srem;
            *reinterpret_cast<short4*>((char*)As + byteA) = a4;
            const short4 b4v = *reinterpret_cast<const short4*>(Bt + (size_t)(col0 + r) * Kd + k0 + skq);
            *reinterpret_cast<short4*>((char*)Bs + byteA) = b4v;
        }
        __syncthreads();

        #pragma unroll
        for (int kk = 0; kk < 2; ++kk) {
            short8 af[4], bfr[4];
            #pragma unroll
            for (int i = 0; i < 4; ++i) {
                const int r = wr * 64 + i * 16 + lr;
                const int byte = r * 128 + (((kk * 4 + lk) ^ (r & 7)) << 4);
                af[i] = *reinterpret_cast<const short8*>((char*)As + byte);
            }
            #pragma unroll
            for (int j = 0; j < 4; ++j) {
                const int r = wc * 64 + j * 16 + lr;
                const int byte = r * 128 + (((kk * 4 + lk) ^ (r & 7)) << 4);
                bfr[j] = *reinterpret_cast<const short8*>((char*)Bs + byte);
            }
            #pragma unroll
            for (int i = 0; i < 4; ++i)
                #pragma unroll
                for (int j = 0; j < 4; ++j)
                    acc[i][j] = __builtin_amdgcn_mfma_f32_16x16x32_bf16(af[i], bfr[j], acc[i][j], 0, 0, 0);
        }
        __syncthreads();
    }

    float*  Cf = (float*)Cp;
    ushort* Cb = (ushort*)Cp;
    #pragma unroll
    for (int j = 0; j < 4; ++j) {
        const int col = col0 + wc * 64 + j * 16 + lr;
        const float bcol = bias[col];
        #pragma unroll
        for (int i = 0; i < 4; ++i) {
            const int rbase = row0 + wr * 64 + i * 16 + lk * 4;
            #pragma unroll
            for (int reg = 0; reg < 4; ++reg) {
                const int r = rbase + reg;
                if (r < Mr) {
                    float v = acc[i][j][reg] + bcol;
                    if (RESID) v += resid[(size_t)r * ldc + col];
                    if (RELU)  v = fmaxf(v, 0.f);
                    if (OUT_BF16) Cb[(size_t)r * ldc + col] = (ushort)f2bf(v);
                    else          Cf[(size_t)r * ldc + col] = v;
                }
            }
        }
    }
}

// ---------------- MHA: bf16 MFMA flash attention ----------------
__global__ __launch_bounds__(256) void attn_mfma(
    const ushort* __restrict__ QKbf, const ushort* __restrict__ Vbf,
    ushort* __restrict__ attnO)
{
    __shared__ ushort K_lds[64][40];
    __shared__ ushort Vt[32][72];
    __shared__ ushort P_lds[4][16][72];

    const int t = threadIdx.x;
    const int w = t >> 6, lane = t & 63;
    const int q0 = blockIdx.x * 64;
    const int m = blockIdx.y & 7, b = blockIdx.y >> 3;

    const int lr = lane & 15;
    const int lk = lane >> 4;

    const int qrow = min(q0 + w * 16 + lr, LQ - 1);
    const short8 qf = *reinterpret_cast<const short8*>(
        QKbf + ((size_t)qrow * BB + b) * 512 + m * 32 + lk * 8);

    f32x4 oacc[2] = {f32x4{0.f,0.f,0.f,0.f}, f32x4{0.f,0.f,0.f,0.f}};
    float mrun[4] = {-1e30f, -1e30f, -1e30f, -1e30f};
    float lrun[4] = {0.f, 0.f, 0.f, 0.f};

    const float scale = 0.17677669529663687f; // 1/sqrt(32)
    const int sr = t >> 2;
    const int sd = (t & 3) * 8;

    for (int k0 = 0; k0 < LQ; k0 += 64) {
        {
            const int kr = min(k0 + sr, LQ - 1);
            *reinterpret_cast<short8*>(&K_lds[sr][sd]) =
                *reinterpret_cast<const short8*>(QKbf + ((size_t)kr * BB + b) * 512 + 256 + m * 32 + sd);
            const short8 v8 = *reinterpret_cast<const short8*>(
                Vbf + ((size_t)kr * BB + b) * 256 + m * 32 + sd);
            #pragma unroll
            for (int j = 0; j < 8; ++j) Vt[sd + j][sr] = (ushort)v8[j];
        }
        __syncthreads();

        f32x4 sa[4];
        #pragma unroll
        for (int n = 0; n < 4; ++n) {
            const short8 kf = *reinterpret_cast<const short8*>(&K_lds[n * 16 + lr][lk * 8]);
            sa[n] = __builtin_amdgcn_mfma_f32_16x16x32_bf16(qf, kf, f32x4{0.f,0.f,0.f,0.f}, 0, 0, 0);
        }
        #pragma unroll
        for (int n = 0; n < 4; ++n)
            #pragma unroll
            for (int r = 0; r < 4; ++r)
                sa[n][r] *= scale;
        if (k0 + 64 > LQ) {
            #pragma unroll
            for (int n = 0; n < 4; ++n)
                if (k0 + n * 16 + lr >= LQ) {
                    #pragma unroll
                    for (int r = 0; r < 4; ++r) sa[n][r] = -1e30f;
                }
        }

        #pragma unroll
        for (int r = 0; r < 4; ++r) {
            float mx = fmaxf(fmaxf(sa[0][r], sa[1][r]), fmaxf(sa[2][r], sa[3][r]));
            #pragma unroll
            for (int o = 8; o; o >>= 1) mx = fmaxf(mx, __shfl_xor(mx, o));
            const float mnew = fmaxf(mrun[r], mx);
            const float corr = __expf(mrun[r] - mnew);
            mrun[r] = mnew;
            float psum = 0.f;
            #pragma unroll
            for (int n = 0; n < 4; ++n) {
                const float p = __expf(sa[n][r] - mnew);
                psum += p;
                P_lds[w][lk * 4 + r][n * 16 + lr] = (ushort)f2bf(p);
            }
            #pragma unroll
            for (int o = 8; o; o >>= 1) psum += __shfl_xor(psum, o);
            lrun[r] = lrun[r] * corr + psum;
            oacc[0][r] *= corr;
            oacc[1][r] *= corr;
        }

        #pragma unroll
        for (int kk = 0; kk < 2; ++kk) {
            const short8 pf = *reinterpret_cast<const short8*>(&P_lds[w][lr][kk * 32 + lk * 8]);
            #pragma unroll
            for (int dt = 0; dt < 2; ++dt) {
                const short8 vf = *reinterpret_cast<const short8*>(&Vt[dt * 16 + lr][kk * 32 + lk * 8]);
                oacc[dt] = __builtin_amdgcn_mfma_f32_16x16x32_bf16(pf, vf, oacc[dt], 0, 0, 0);
            }
        }
        __syncthreads();
    }

    #pragma unroll
    for (int r = 0; r < 4; ++r) {
        const int row = q0 + w * 16 + lk * 4 + r;
        if (row < LQ) {
            const float inv = 1.f / lrun[r];
            ushort* op = attnO + ((size_t)row * BB + b) * 256 + m * 32;
            op[lr]      = (ushort)f2bf(oacc[0][r] * inv);
            op[16 + lr] = (ushort)f2bf(oacc[1][r] * inv);
        }
    }
}

// ---------------- layernorm: one wave per row of 256 ----------------
__global__ __launch_bounds__(256) void ln_kernel(
    const float* __restrict__ X, const float* __restrict__ g,
    const float* __restrict__ bta, float* __restrict__ Y, int nrows)
{
    const int r = blockIdx.x * 4 + (threadIdx.x >> 6);
    if (r >= nrows) return;
    const int lane = threadIdx.x & 63;
    const float4 v = *reinterpret_cast<const float4*>(X + (size_t)r * 256 + lane * 4);
    float s  = v.x + v.y + v.z + v.w;
    float sq = v.x * v.x + v.y * v.y + v.z * v.z + v.w * v.w;
    #pragma unroll
    for (int o = 32; o; o >>= 1) { s += __shfl_xor(s, o); sq += __shfl_xor(sq, o); }
    const float mean = s * (1.f / 256.f);
    const float var  = sq * (1.f / 256.f) - mean * mean;
    const float rs   = rsqrtf(var + 1e-5f);
    const float4 gv = *reinterpret_cast<const float4*>(g + lane * 4);
    const float4 bv = *reinterpret_cast<const float4*>(bta + lane * 4);
    float4 o4;
    o4.x = (v.x - mean) * rs * gv.x + bv.x;
    o4.y = (v.y - mean) * rs * gv.y + bv.y;
    o4.z = (v.z - mean) * rs * gv.z + bv.z;
    o4.w = (v.w - mean) * rs * gv.w + bv.w;
    *reinterpret_cast<float4*>(Y + (size_t)r * 256 + lane * 4) = o4;
}

// ---------------- sampling prep: one thread per (row,m,l,k) ----------------
// Fuses the L*K softmax (16-lane shfl groups) and computes 4 bilinear corners:
// global value-row index + combined weight (aw * bilinear * valid).
__global__ __launch_bounds__(256) void samp_prep(
    const float* __restrict__ ref, const float* __restrict__ offb,
    const float* __restrict__ awl, int4* __restrict__ prepI, float4* __restrict__ prepW)
{
    const int gid = blockIdx.x * 256 + threadIdx.x;   // < 1,843,200
    const int k = gid & 3, l = (gid >> 2) & 3, m = (gid >> 4) & 7, row = gid >> 7;
    const int b = row & 15;

    // softmax over the 16 (l,k) lanes sharing (row,m)
    const float logit = awl[(size_t)row * 128 + m * 16 + l * 4 + k];
    float mx = logit;
    #pragma unroll
    for (int o = 1; o < 16; o <<= 1) mx = fmaxf(mx, __shfl_xor(mx, o));
    const float e = __expf(logit - mx);
    float se = e;
    #pragma unroll
    for (int o = 1; o < 16; o <<= 1) se += __shfl_xor(se, o);
    const float aw = e / se;

    const int   Hl = d_HW[l];
    const float Hf = (float)Hl;
    const int   gbase = d_baseR[l] + b * Hl * Hl;
    const float rx = ref[row * 2 + 0], ry = ref[row * 2 + 1];
    const float ox = offb[(size_t)row * 256 + m * 32 + l * 8 + k * 2 + 0];
    const float oy = offb[(size_t)row * 256 + m * 32 + l * 8 + k * 2 + 1];
    const float px = rx * Hf - 0.5f + ox;
    const float py = ry * Hf - 0.5f + oy;
    const float x0 = floorf(px), y0 = floorf(py);

    int4 I; float4 W;
    #pragma unroll
    for (int c = 0; c < 4; ++c) {
        const float xi = x0 + (float)(c & 1);
        const float yi = y0 + (float)(c >> 1);
        const float wv = (1.f - fabsf(px - xi)) * (1.f - fabsf(py - yi));
        const bool valid = (xi >= 0.f) && (xi < Hf) && (yi >= 0.f) && (yi < Hf);
        const int ix = min(max((int)xi, 0), Hl - 1);
        const int iy = min(max((int)yi, 0), Hl - 1);
        const int idx = gbase + iy * Hl + ix;
        const float wgt = valid ? aw * wv : 0.f;
        if (c == 0) { I.x = idx; W.x = wgt; }
        else if (c == 1) { I.y = idx; W.y = wgt; }
        else if (c == 2) { I.z = idx; W.z = wgt; }
        else { I.w = idx; W.w = wgt; }
    }
    prepI[gid] = I;
    prepW[gid] = W;
}

// ---------------- sampling gather: one wave per (q,b,m); lane=(sid,d2) ----------------
__global__ __launch_bounds__(256) void samp_gather(
    const ushort* __restrict__ Vval, const int4* __restrict__ prepI,
    const float4* __restrict__ prepW, float* __restrict__ samp)
{
    const int wid  = blockIdx.x * 4 + (threadIdx.x >> 6);  // < 115,200
    const int lane = threadIdx.x & 63;
    const int q  = wid % LQ;
    const int bm = wid / LQ;
    const int m  = bm & 7, b = bm >> 3;
    const int row = q * BB + b;
    const int sid = lane >> 4, d2 = lane & 15;

    const uint* V2 = (const uint*)Vval;            // 2 bf16 channels per uint
    const int pbase = (row * 8 + m) * 16;
    const int coff  = m * 16 + d2;

    float a0 = 0.f, a1 = 0.f;
    #pragma unroll
    for (int g = 0; g < 4; ++g) {
        const int4   I = prepI[pbase + g * 4 + sid];
        const float4 W = prepW[pbase + g * 4 + sid];
        uint v;
        v = V2[(size_t)I.x * 128 + coff];
        a0 += W.x * bf2f((ushort)v); a1 += W.x * bf2f((ushort)(v >> 16));
        v = V2[(size_t)I.y * 128 + coff];
        a0 += W.y * bf2f((ushort)v); a1 += W.y * bf2f((ushort)(v >> 16));
        v = V2[(size_t)I.z * 128 + coff];
        a0 += W.z * bf2f((ushort)v); a1 += W.z * bf2f((ushort)(v >> 16));
        v = V2[(size_t)I.w * 128 + coff];
        a0 += W.w * bf2f((ushort)v); a1 += W.w * bf2f((ushort)(v >> 16));
    }
    a0 += __shfl_xor(a0, 16); a0 += __shfl_xor(a0, 32);
    a1 += __shfl_xor(a1, 16); a1 += __shfl_xor(a1, 32);
    if (lane < 16) {
        float2 o2; o2.x = a0; o2.y = a1;
        *reinterpret_cast<float2*>(samp + (size_t)row * 256 + m * 32 + d2 * 2) = o2;
    }
}

// ---------------- launcher ----------------
extern "C" void kernel_launch(void* const* d_in, const int* in_sizes, int n_in,
                              void* d_out, int out_size, void* d_ws, size_t ws_size,
                              hipStream_t stream)
{
    const float* qo   = (const float*)d_in[0];
    const float* qpz  = (const float*)d_in[1];
    const float* refp = (const float*)d_in[2];
    const float* feat[4] = {(const float*)d_in[3], (const float*)d_in[5],
                            (const float*)d_in[7], (const float*)d_in[9]};
    const float* pos[4]  = {(const float*)d_in[4], (const float*)d_in[6],
                            (const float*)d_in[8], (const float*)d_in[10]};
    const float* sa_in_w  = (const float*)d_in[11];
    const float* sa_in_b  = (const float*)d_in[12];
    const float* sa_out_w = (const float*)d_in[13];
    const float* sa_out_b = (const float*)d_in[14];
    const float* n1_g = (const float*)d_in[15];
    const float* n1_b = (const float*)d_in[16];
    const float* n2_g = (const float*)d_in[17];
    const float* n2_b = (const float*)d_in[18];
    const float* n3_g = (const float*)d_in[19];
    const float* n3_b = (const float*)d_in[20];
    const float* val_w  = (const float*)d_in[21];
    const float* val_b  = (const float*)d_in[22];
    const float* off_w  = (const float*)d_in[23];
    const float* off_b  = (const float*)d_in[24];
    const float* aw_w   = (const float*)d_in[25];
    const float* aw_b   = (const float*)d_in[26];
    const float* dout_w = (const float*)d_in[27];
    const float* dout_b = (const float*)d_in[28];
    const float* ffn_w1 = (const float*)d_in[29];
    const float* ffn_b1 = (const float*)d_in[30];
    const float* ffn_w2 = (const float*)d_in[31];
    const float* ffn_b2 = (const float*)d_in[32];

    char* ws = (char*)d_ws;
    // bf16 buffers
    ushort* QKbf   = (ushort*)(ws + 0);             // 14,745,600
    ushort* Vbf    = (ushort*)(ws + 14745600);      // 7,372,800
    ushort* attnO  = (ushort*)(ws + 22118400);      // 7,372,800
    ushort* Vval   = (ushort*)(ws + 29491200);      // 108,904,448
    ushort* WsaInT = (ushort*)(ws + 138395648);     // 393,216
    ushort* WsaOutT= (ushort*)(ws + 138788864);     // 131,072
    ushort* WvalT  = (ushort*)(ws + 138919936);     // 131,072
    ushort* WdoutT = (ushort*)(ws + 139051008);     // 131,072
    ushort* Wffn1T = (ushort*)(ws + 139182080);     // 524,288
    ushort* Wffn2T = (ushort*)(ws + 139706368);     // 524,288
    // f32 buffers
    float* x1   = (float*)(ws + 140230656);         // 14,745,600
    float* dres = x1;
    float* xln1 = (float*)(ws + 154976256);         // 14,745,600
    float* offb = (float*)(ws + 169721856);         // 14,745,600
    float* x3   = offb;                             // alias (offb dead after samp_prep)
    float* awb  = (float*)(ws + 184467456);         // 7,372,800 (logits)
    float* samp = (float*)(ws + 191840256);         // 14,745,600
    float* xln2 = (float*)(ws + 206585856);         // 14,745,600
    ushort* h   = (ushort*)(ws + 221331456);        // 29,491,200 (bf16 hidden)
    int4*  prepI = (int4*)(ws + 250822656);         // 29,491,200
    float4* prepW = (float4*)(ws + 280313856);      // 29,491,200 -> ends 309,805,056

    const dim3 blk(256);
    const int GM = (NROWS + 127) / 128;             // 113

    // 0. weight transpose+convert to bf16 (N,K)
    conv_w_T<<<dim3(24, 8), blk, 0, stream>>>(sa_in_w, WsaInT, 256, 768);
    conv_w_T<<<dim3(8, 8), blk, 0, stream>>>(sa_out_w, WsaOutT, 256, 256);
    conv_w_T<<<dim3(8, 8), blk, 0, stream>>>(val_w, WvalT, 256, 256);
    conv_w_T<<<dim3(8, 8), blk, 0, stream>>>(dout_w, WdoutT, 256, 256);
    conv_w_T<<<dim3(32, 8), blk, 0, stream>>>(ffn_w1, Wffn1T, 256, 1024);
    conv_w_T<<<dim3(8, 32), blk, 0, stream>>>(ffn_w2, Wffn2T, 1024, 256);

    // 1. Q,K projections -> QKbf
    gemm_bf16<false, true, false, false, true><<<dim3(4, GM), blk, 0, stream>>>(
        qo, qpz, 256, WsaInT, sa_in_b, nullptr, QKbf, 512, NROWS, 256);
    // 2. V projection -> Vbf
    gemm_bf16<false, false, false, false, true><<<dim3(2, GM), blk, 0, stream>>>(
        qo, nullptr, 256, WsaInT + 512 * 256, sa_in_b + 512, nullptr, Vbf, 256, NROWS, 256);
    // 3. self-attention
    attn_mfma<<<dim3(15, 128), blk, 0, stream>>>(QKbf, Vbf, attnO);
    // 4. out projection + residual(qo) -> x1 f32
    gemm_bf16<true, false, false, true, false><<<dim3(2, GM), blk, 0, stream>>>(
        attnO, nullptr, 256, WsaOutT, sa_out_b, qo, x1, 256, NROWS, 256);
    // 5. LN1
    ln_kernel<<<dim3(3600), blk, 0, stream>>>(x1, n1_g, n1_b, xln1, NROWS);
    // 6. sampling offsets -> offb f32 [f32 engine — group A]
    gemm_f32<false, false, false><<<dim3(4, 225), blk, 0, stream>>>(
        xln1, nullptr, 256, off_w, 256, off_b, nullptr, offb, 256, NROWS, 256, 256);
    // 7. attention-weight logits -> awb f32 [f32 engine — group A]
    gemm_f32<false, false, false><<<dim3(2, 225), blk, 0, stream>>>(
        xln1, nullptr, 256, aw_w, 128, aw_b, nullptr, awb, 128, NROWS, 128, 256);
    // 8. sampling prep (softmax fused) -> prepI/prepW
    samp_prep<<<dim3(7200), blk, 0, stream>>>(refp, offb, awb, prepI, prepW);
    // 9. value projections per level -> Vval bf16
    gemm_bf16<false, true, false, false, true><<<dim3(2, 1250), blk, 0, stream>>>(
        feat[0], pos[0], 256, WvalT, val_b, nullptr, Vval, 256, 160000, 256);
    gemm_bf16<false, true, false, false, true><<<dim3(2, 313), blk, 0, stream>>>(
        feat[1], pos[1], 256, WvalT, val_b, nullptr, Vval + (size_t)160000 * 256, 256, 40000, 256);
    gemm_bf16<false, true, false, false, true><<<dim3(2, 79), blk, 0, stream>>>(
        feat[2], pos[2], 256, WvalT, val_b, nullptr, Vval + (size_t)200000 * 256, 256, 10000, 256);
    gemm_bf16<false, true, false, false, true><<<dim3(2, 22), blk, 0, stream>>>(
        feat[3], pos[3], 256, WvalT, val_b, nullptr, Vval + (size_t)210000 * 256, 256, 2704, 256);
    // 10. gather -> samp f32
    samp_gather<<<dim3(28800), blk, 0, stream>>>(Vval, prepI, prepW, samp);
    // 11. deform output projection + residual(xln1) -> dres f32 [bf16 engine — group B]
    gemm_bf16<false, false, false, true, false><<<dim3(2, GM), blk, 0, stream>>>(
        samp, nullptr, 256, WdoutT, dout_b, xln1, dres, 256, NROWS, 256);
    // 12. LN2
    ln_kernel<<<dim3(3600), blk, 0, stream>>>(dres, n2_g, n2_b, xln2, NROWS);
    // 13. FFN1 (relu) -> h bf16 [bf16 engine — group B]
    gemm_bf16<false, false, true, false, true><<<dim3(8, GM), blk, 0, stream>>>(
        xln2, nullptr, 256, Wffn1T, ffn_b1, nullptr, h, 1024, NROWS, 256);
    // 14. FFN2 + residual(xln2) -> x3 f32 [bf16 engine — group B]
    gemm_bf16<true, false, false, true, false><<<dim3(2, GM), blk, 0, stream>>>(
        h, nullptr, 1024, Wffn2T, ffn_b2, xln2, x3, 256, NROWS, 1024);
    // 15. LN3 -> output
    ln_kernel<<<dim3(3600), blk, 0, stream>>>(x3, n3_g, n3_b, (float*)d_out, NROWS);
}

// Round 7
// 601.162 us; speedup vs baseline: 6.9149x; 1.3025x over previous
//
#include <hip/hip_runtime.h>
#include <hip/hip_bf16.h>
#include <cstdint>

// ---------------- constants ----------------
#define LQ 900
#define BB 16
#define CC 256
#define MM 8
#define CV 32
#define NROWS (LQ * BB)   // 14400

typedef __attribute__((ext_vector_type(8))) short short8;
typedef __attribute__((ext_vector_type(4))) float f32x4;

__device__ __forceinline__ short f2bf(float f) {
    union { float f; unsigned u; } x; x.f = f;
    const unsigned r = x.u + 0x7fff + ((x.u >> 16) & 1);
    return (short)(r >> 16);
}
__device__ __forceinline__ float bf2f(ushort u) {
    union { unsigned u; float f; } c; c.u = ((unsigned)u) << 16; return c.f;
}

// level geometry (square levels)
__device__ __constant__ int d_HW[4]    = {100, 50, 25, 13};
__device__ __constant__ int d_baseR[4] = {0, 160000, 200000, 210000};

// ---------------- weight transpose+convert: W(K,N) f32 -> Wt(N,K) bf16 ----------------
__global__ __launch_bounds__(256) void conv_w_T(
    const float* __restrict__ W, ushort* __restrict__ Wt, int K, int N)
{
    __shared__ float tl[32][33];
    const int t = threadIdx.x;
    const int tx = t & 31, ty = t >> 5;
    const int n0 = blockIdx.x * 32, k0 = blockIdx.y * 32;
    #pragma unroll
    for (int p = 0; p < 4; ++p)
        tl[ty + 8 * p][tx] = W[(size_t)(k0 + ty + 8 * p) * N + n0 + tx];
    __syncthreads();
    #pragma unroll
    for (int p = 0; p < 4; ++p)
        Wt[(size_t)(n0 + ty + 8 * p) * K + k0 + tx] = (ushort)f2bf(tl[tx][ty + 8 * p]);
}

// ---------------- tiny bias concat: [off_b(256) | aw_b(128)] ----------------
// FIX R7: use global thread id (was threadIdx-only -> cols 256..383 never written)
__global__ void concat_bias(const float* __restrict__ a, const float* __restrict__ b,
                            float* __restrict__ o)
{
    const int t = blockIdx.x * 256 + threadIdx.x;
    if (t < 384) o[t] = (t < 256) ? a[t] : b[t - 256];
}

// ---------------- bf16 MFMA GEMM v2: reg-prefetch + coalesced bf16 epilogue ----
// C[M,N] = (A(+A2)) @ Wt^T + bias (+resid)(relu). Wt (N,K) bf16 row-major.
// 128x128 tile, BK=64, 4 waves 2x2, LDS XOR-swizzled (granule ^= row&7).
template<bool A_BF16, bool ADD_A2, bool RELU, bool RESID, bool OUT_BF16>
__global__ __launch_bounds__(256) void gemm_bf16(
    const void* __restrict__ Ap, const float* __restrict__ A2, int lda,
    const ushort* __restrict__ Bt, const float* __restrict__ bias,
    const float* __restrict__ resid, void* __restrict__ Cp, int ldc,
    int Mr, int Kd)
{
    __shared__ ushort lds[16384];          // 32KB: As = [0,8192), Bs = [8192,16384)
    ushort* As = lds;
    ushort* Bs = lds + 8192;

    const int t = threadIdx.x;
    const int lane = t & 63;
    const int w = t >> 6;
    const int wr = w >> 1, wc = w & 1;
    const int lr = lane & 15, lk = lane >> 4;
    const int row0 = blockIdx.y * 128;
    const int col0 = blockIdx.x * 128;

    f32x4 acc[4][4] = {};

    const int srow = t >> 4;          // 0..15
    const int skq  = (t & 15) * 4;    // k-offset in elements
    const int sg   = (t & 15) >> 1;   // 16B granule 0..7
    const int srem = (t & 1) * 8;     // byte remainder within granule

    const float*  Af = (const float*)Ap;
    const ushort* Ah = (const ushort*)Ap;

    // staging registers (issue-early / write-late)
    short4 sa_[8], sb_[8];
    float4 fa_[8], f2_[8];

    const int nk = Kd >> 6;

    // ---- issue loads for k-tile kk0 ----
    auto issue = [&](int kk0) {
        #pragma unroll
        for (int p = 0; p < 8; ++p) {
            const int gr = min(row0 + p * 16 + srow, Mr - 1);
            if constexpr (A_BF16) {
                sa_[p] = *reinterpret_cast<const short4*>(Ah + (size_t)gr * lda + kk0 + skq);
            } else {
                fa_[p] = *reinterpret_cast<const float4*>(Af + (size_t)gr * lda + kk0 + skq);
                if constexpr (ADD_A2)
                    f2_[p] = *reinterpret_cast<const float4*>(A2 + (size_t)gr * lda + kk0 + skq);
            }
            sb_[p] = *reinterpret_cast<const short4*>(Bt + (size_t)(col0 + p * 16 + srow) * Kd + kk0 + skq);
        }
    };

    issue(0);

    for (int kt = 0; kt < nk; ++kt) {
        // ---- write staged regs to LDS ----
        #pragma unroll
        for (int p = 0; p < 8; ++p) {
            const int r = p * 16 + srow;
            short4 a4;
            if constexpr (A_BF16) {
                a4 = sa_[p];
            } else {
                float4 av = fa_[p];
                if constexpr (ADD_A2) {
                    av.x += f2_[p].x; av.y += f2_[p].y; av.z += f2_[p].z; av.w += f2_[p].w;
                }
                a4.x = f2bf(av.x); a4.y = f2bf(av.y); a4.z = f2bf(av.z); a4.w = f2bf(av.w);
            }
            const int byteA = r * 128 + ((sg ^ (r & 7)) << 4) + srem;
            *reinterpret_cast<short4*>((char*)As + byteA) = a4;
            *reinterpret_cast<short4*>((char*)Bs + byteA) = sb_[p];
        }
        __syncthreads();

        // ---- prefetch next tile (flies during MFMA phase) ----
        if (kt + 1 < nk) issue((kt + 1) * 64);

        // ---- MFMA phase ----
        #pragma unroll
        for (int kk = 0; kk < 2; ++kk) {
            short8 af[4], bfr[4];
            #pragma unroll
            for (int i = 0; i < 4; ++i) {
                const int r = wr * 64 + i * 16 + lr;
                const int byte = r * 128 + (((kk * 4 + lk) ^ (r & 7)) << 4);
                af[i] = *reinterpret_cast<const short8*>((char*)As + byte);
            }
            #pragma unroll
            for (int j = 0; j < 4; ++j) {
                const int r = wc * 64 + j * 16 + lr;
                const int byte = r * 128 + (((kk * 4 + lk) ^ (r & 7)) << 4);
                bfr[j] = *reinterpret_cast<const short8*>((char*)Bs + byte);
            }
            #pragma unroll
            for (int i = 0; i < 4; ++i)
                #pragma unroll
                for (int j = 0; j < 4; ++j)
                    acc[i][j] = __builtin_amdgcn_mfma_f32_16x16x32_bf16(af[i], bfr[j], acc[i][j], 0, 0, 0);
        }
        __syncthreads();
    }

    if constexpr (OUT_BF16) {
        // stage full 128x128 bf16 tile in LDS, then write coalesced 128B halves
        ushort* Cb = (ushort*)Cp;
        #pragma unroll
        for (int j = 0; j < 4; ++j) {
            const int lcol = wc * 64 + j * 16 + lr;
            const float bcol = bias[col0 + lcol];
            #pragma unroll
            for (int i = 0; i < 4; ++i) {
                const int lrbase = wr * 64 + i * 16 + lk * 4;
                #pragma unroll
                for (int reg = 0; reg < 4; ++reg) {
                    float v = acc[i][j][reg] + bcol;
                    if (RELU) v = fmaxf(v, 0.f);
                    lds[(lrbase + reg) * 128 + lcol] = (ushort)f2bf(v);
                }
            }
        }
        __syncthreads();
        // FIX R7: each thread owns 64 ushorts (8 x short8), was 4 (half-written tile)
        const int erow = t >> 1, ehalf = t & 1;
        if (row0 + erow < Mr) {
            ushort* dst = Cb + (size_t)(row0 + erow) * ldc + col0 + ehalf * 64;
            const ushort* src = lds + erow * 128 + ehalf * 64;
            #pragma unroll
            for (int q = 0; q < 8; ++q)
                *reinterpret_cast<short8*>(dst + q * 8) =
                    *reinterpret_cast<const short8*>(src + q * 8);
        }
    } else {
        float* Cf = (float*)Cp;
        #pragma unroll
        for (int j = 0; j < 4; ++j) {
            const int col = col0 + wc * 64 + j * 16 + lr;
            const float bcol = bias[col];
            #pragma unroll
            for (int i = 0; i < 4; ++i) {
                const int rbase = row0 + wr * 64 + i * 16 + lk * 4;
                #pragma unroll
                for (int reg = 0; reg < 4; ++reg) {
                    const int r = rbase + reg;
                    if (r < Mr) {
                        float v = acc[i][j][reg] + bcol;
                        if (RESID) v += resid[(size_t)r * ldc + col];
                        if (RELU)  v = fmaxf(v, 0.f);
                        Cf[(size_t)r * ldc + col] = v;
                    }
                }
            }
        }
    }
}

// ---------------- MHA: bf16 MFMA flash attention ----------------
__global__ __launch_bounds__(256) void attn_mfma(
    const ushort* __restrict__ QKbf, const ushort* __restrict__ Vbf,
    ushort* __restrict__ attnO)
{
    __shared__ ushort K_lds[64][40];
    __shared__ ushort Vt[32][72];
    __shared__ ushort P_lds[4][16][72];

    const int t = threadIdx.x;
    const int w = t >> 6, lane = t & 63;
    const int q0 = blockIdx.x * 64;
    const int m = blockIdx.y & 7, b = blockIdx.y >> 3;

    const int lr = lane & 15;
    const int lk = lane >> 4;

    const int qrow = min(q0 + w * 16 + lr, LQ - 1);
    const short8 qf = *reinterpret_cast<const short8*>(
        QKbf + ((size_t)qrow * BB + b) * 512 + m * 32 + lk * 8);

    f32x4 oacc[2] = {f32x4{0.f,0.f,0.f,0.f}, f32x4{0.f,0.f,0.f,0.f}};
    float mrun[4] = {-1e30f, -1e30f, -1e30f, -1e30f};
    float lrun[4] = {0.f, 0.f, 0.f, 0.f};

    const float scale = 0.17677669529663687f; // 1/sqrt(32)
    const int sr = t >> 2;
    const int sd = (t & 3) * 8;

    for (int k0 = 0; k0 < LQ; k0 += 64) {
        {
            const int kr = min(k0 + sr, LQ - 1);
            *reinterpret_cast<short8*>(&K_lds[sr][sd]) =
                *reinterpret_cast<const short8*>(QKbf + ((size_t)kr * BB + b) * 512 + 256 + m * 32 + sd);
            const short8 v8 = *reinterpret_cast<const short8*>(
                Vbf + ((size_t)kr * BB + b) * 256 + m * 32 + sd);
            #pragma unroll
            for (int j = 0; j < 8; ++j) Vt[sd + j][sr] = (ushort)v8[j];
        }
        __syncthreads();

        f32x4 sa[4];
        #pragma unroll
        for (int n = 0; n < 4; ++n) {
            const short8 kf = *reinterpret_cast<const short8*>(&K_lds[n * 16 + lr][lk * 8]);
            sa[n] = __builtin_amdgcn_mfma_f32_16x16x32_bf16(qf, kf, f32x4{0.f,0.f,0.f,0.f}, 0, 0, 0);
        }
        #pragma unroll
        for (int n = 0; n < 4; ++n)
            #pragma unroll
            for (int r = 0; r < 4; ++r)
                sa[n][r] *= scale;
        if (k0 + 64 > LQ) {
            #pragma unroll
            for (int n = 0; n < 4; ++n)
                if (k0 + n * 16 + lr >= LQ) {
                    #pragma unroll
                    for (int r = 0; r < 4; ++r) sa[n][r] = -1e30f;
                }
        }

        #pragma unroll
        for (int r = 0; r < 4; ++r) {
            float mx = fmaxf(fmaxf(sa[0][r], sa[1][r]), fmaxf(sa[2][r], sa[3][r]));
            #pragma unroll
            for (int o = 8; o; o >>= 1) mx = fmaxf(mx, __shfl_xor(mx, o));
            const float mnew = fmaxf(mrun[r], mx);
            const float corr = __expf(mrun[r] - mnew);
            mrun[r] = mnew;
            float psum = 0.f;
            #pragma unroll
            for (int n = 0; n < 4; ++n) {
                const float p = __expf(sa[n][r] - mnew);
                psum += p;
                P_lds[w][lk * 4 + r][n * 16 + lr] = (ushort)f2bf(p);
            }
            #pragma unroll
            for (int o = 8; o; o >>= 1) psum += __shfl_xor(psum, o);
            lrun[r] = lrun[r] * corr + psum;
            oacc[0][r] *= corr;
            oacc[1][r] *= corr;
        }

        #pragma unroll
        for (int kk = 0; kk < 2; ++kk) {
            const short8 pf = *reinterpret_cast<const short8*>(&P_lds[w][lr][kk * 32 + lk * 8]);
            #pragma unroll
            for (int dt = 0; dt < 2; ++dt) {
                const short8 vf = *reinterpret_cast<const short8*>(&Vt[dt * 16 + lr][kk * 32 + lk * 8]);
                oacc[dt] = __builtin_amdgcn_mfma_f32_16x16x32_bf16(pf, vf, oacc[dt], 0, 0, 0);
            }
        }
        __syncthreads();
    }

    #pragma unroll
    for (int r = 0; r < 4; ++r) {
        const int row = q0 + w * 16 + lk * 4 + r;
        if (row < LQ) {
            const float inv = 1.f / lrun[r];
            ushort* op = attnO + ((size_t)row * BB + b) * 256 + m * 32;
            op[lr]      = (ushort)f2bf(oacc[0][r] * inv);
            op[16 + lr] = (ushort)f2bf(oacc[1][r] * inv);
        }
    }
}

// ---------------- layernorm: one wave per row of 256 ----------------
__global__ __launch_bounds__(256) void ln_kernel(
    const float* __restrict__ X, const float* __restrict__ g,
    const float* __restrict__ bta, float* __restrict__ Y, int nrows)
{
    const int r = blockIdx.x * 4 + (threadIdx.x >> 6);
    if (r >= nrows) return;
    const int lane = threadIdx.x & 63;
    const float4 v = *reinterpret_cast<const float4*>(X + (size_t)r * 256 + lane * 4);
    float s  = v.x + v.y + v.z + v.w;
    float sq = v.x * v.x + v.y * v.y + v.z * v.z + v.w * v.w;
    #pragma unroll
    for (int o = 32; o; o >>= 1) { s += __shfl_xor(s, o); sq += __shfl_xor(sq, o); }
    const float mean = s * (1.f / 256.f);
    const float var  = sq * (1.f / 256.f) - mean * mean;
    const float rs   = rsqrtf(var + 1e-5f);
    const float4 gv = *reinterpret_cast<const float4*>(g + lane * 4);
    const float4 bv = *reinterpret_cast<const float4*>(bta + lane * 4);
    float4 o4;
    o4.x = (v.x - mean) * rs * gv.x + bv.x;
    o4.y = (v.y - mean) * rs * gv.y + bv.y;
    o4.z = (v.z - mean) * rs * gv.z + bv.z;
    o4.w = (v.w - mean) * rs * gv.w + bv.w;
    *reinterpret_cast<float4*>(Y + (size_t)r * 256 + lane * 4) = o4;
}

// ---------------- sampling prep: one thread per (row,m,l,k) ----------------
// obf: (NROWS, 384) f32 — cols 0..255 offsets, 256..383 aw logits.
__global__ __launch_bounds__(256) void samp_prep(
    const float* __restrict__ ref, const float* __restrict__ obf,
    int4* __restrict__ prepI, float4* __restrict__ prepW)
{
    const int gid = blockIdx.x * 256 + threadIdx.x;   // < 1,843,200
    const int k = gid & 3, l = (gid >> 2) & 3, m = (gid >> 4) & 7, row = gid >> 7;
    const int b = row & 15;

    // softmax over the 16 (l,k) lanes sharing (row,m)
    const float logit = obf[(size_t)row * 384 + 256 + m * 16 + l * 4 + k];
    float mx = logit;
    #pragma unroll
    for (int o = 1; o < 16; o <<= 1) mx = fmaxf(mx, __shfl_xor(mx, o));
    const float e = __expf(logit - mx);
    float se = e;
    #pragma unroll
    for (int o = 1; o < 16; o <<= 1) se += __shfl_xor(se, o);
    const float aw = e / se;

    const int   Hl = d_HW[l];
    const float Hf = (float)Hl;
    const int   gbase = d_baseR[l] + b * Hl * Hl;
    const float rx = ref[row * 2 + 0], ry = ref[row * 2 + 1];
    const float ox = obf[(size_t)row * 384 + m * 32 + l * 8 + k * 2 + 0];
    const float oy = obf[(size_t)row * 384 + m * 32 + l * 8 + k * 2 + 1];
    const float px = rx * Hf - 0.5f + ox;
    const float py = ry * Hf - 0.5f + oy;
    const float x0 = floorf(px), y0 = floorf(py);

    int4 I; float4 W;
    #pragma unroll
    for (int c = 0; c < 4; ++c) {
        const float xi = x0 + (float)(c & 1);
        const float yi = y0 + (float)(c >> 1);
        const float wv = (1.f - fabsf(px - xi)) * (1.f - fabsf(py - yi));
        const bool valid = (xi >= 0.f) && (xi < Hf) && (yi >= 0.f) && (yi < Hf);
        const int ix = min(max((int)xi, 0), Hl - 1);
        const int iy = min(max((int)yi, 0), Hl - 1);
        const int idx = gbase + iy * Hl + ix;
        const float wgt = valid ? aw * wv : 0.f;
        if (c == 0) { I.x = idx; W.x = wgt; }
        else if (c == 1) { I.y = idx; W.y = wgt; }
        else if (c == 2) { I.z = idx; W.z = wgt; }
        else { I.w = idx; W.w = wgt; }
    }
    prepI[gid] = I;
    prepW[gid] = W;
}

// ---------------- sampling gather: one wave per (q,b,m); lane=(sid,d2) ----------------
__global__ __launch_bounds__(256) void samp_gather(
    const ushort* __restrict__ Vval, const int4* __restrict__ prepI,
    const float4* __restrict__ prepW, float* __restrict__ samp)
{
    const int wid  = blockIdx.x * 4 + (threadIdx.x >> 6);  // < 115,200
    const int lane = threadIdx.x & 63;
    const int q  = wid % LQ;
    const int bm = wid / LQ;
    const int m  = bm & 7, b = bm >> 3;
    const int row = q * BB + b;
    const int sid = lane >> 4, d2 = lane & 15;

    const uint* V2 = (const uint*)Vval;            // 2 bf16 channels per uint
    const int pbase = (row * 8 + m) * 16;
    const int coff  = m * 16 + d2;

    float a0 = 0.f, a1 = 0.f;
    #pragma unroll
    for (int g = 0; g < 4; ++g) {
        const int4   I = prepI[pbase + g * 4 + sid];
        const float4 W = prepW[pbase + g * 4 + sid];
        uint v;
        v = V2[(size_t)I.x * 128 + coff];
        a0 += W.x * bf2f((ushort)v); a1 += W.x * bf2f((ushort)(v >> 16));
        v = V2[(size_t)I.y * 128 + coff];
        a0 += W.y * bf2f((ushort)v); a1 += W.y * bf2f((ushort)(v >> 16));
        v = V2[(size_t)I.z * 128 + coff];
        a0 += W.z * bf2f((ushort)v); a1 += W.z * bf2f((ushort)(v >> 16));
        v = V2[(size_t)I.w * 128 + coff];
        a0 += W.w * bf2f((ushort)v); a1 += W.w * bf2f((ushort)(v >> 16));
    }
    a0 += __shfl_xor(a0, 16); a0 += __shfl_xor(a0, 32);
    a1 += __shfl_xor(a1, 16); a1 += __shfl_xor(a1, 32);
    if (lane < 16) {
        float2 o2; o2.x = a0; o2.y = a1;
        *reinterpret_cast<float2*>(samp + (size_t)row * 256 + m * 32 + d2 * 2) = o2;
    }
}

// ---------------- launcher ----------------
extern "C" void kernel_launch(void* const* d_in, const int* in_sizes, int n_in,
                              void* d_out, int out_size, void* d_ws, size_t ws_size,
                              hipStream_t stream)
{
    const float* qo   = (const float*)d_in[0];
    const float* qpz  = (const float*)d_in[1];
    const float* refp = (const float*)d_in[2];
    const float* feat[4] = {(const float*)d_in[3], (const float*)d_in[5],
                            (const float*)d_in[7], (const float*)d_in[9]};
    const float* pos[4]  = {(const float*)d_in[4], (const float*)d_in[6],
                            (const float*)d_in[8], (const float*)d_in[10]};
    const float* sa_in_w  = (const float*)d_in[11];
    const float* sa_in_b  = (const float*)d_in[12];
    const float* sa_out_w = (const float*)d_in[13];
    const float* sa_out_b = (const float*)d_in[14];
    const float* n1_g = (const float*)d_in[15];
    const float* n1_b = (const float*)d_in[16];
    const float* n2_g = (const float*)d_in[17];
    const float* n2_b = (const float*)d_in[18];
    const float* n3_g = (const float*)d_in[19];
    const float* n3_b = (const float*)d_in[20];
    const float* val_w  = (const float*)d_in[21];
    const float* val_b  = (const float*)d_in[22];
    const float* off_w  = (const float*)d_in[23];
    const float* off_b  = (const float*)d_in[24];
    const float* aw_w   = (const float*)d_in[25];
    const float* aw_b   = (const float*)d_in[26];
    const float* dout_w = (const float*)d_in[27];
    const float* dout_b = (const float*)d_in[28];
    const float* ffn_w1 = (const float*)d_in[29];
    const float* ffn_b1 = (const float*)d_in[30];
    const float* ffn_w2 = (const float*)d_in[31];
    const float* ffn_b2 = (const float*)d_in[32];

    char* ws = (char*)d_ws;
    // bf16 buffers
    ushort* QKbf   = (ushort*)(ws + 0);             // 14,745,600
    ushort* Vbf    = (ushort*)(ws + 14745600);      // 7,372,800
    ushort* attnO  = (ushort*)(ws + 22118400);      // 7,372,800
    ushort* Vval   = (ushort*)(ws + 29491200);      // 108,904,448
    ushort* WsaInT = (ushort*)(ws + 138395648);     // 393,216
    ushort* WsaOutT= (ushort*)(ws + 138788864);     // 131,072
    ushort* WvalT  = (ushort*)(ws + 138919936);     // 131,072
    ushort* WdoutT = (ushort*)(ws + 139051008);     // 131,072
    ushort* Wffn1T = (ushort*)(ws + 139182080);     // 524,288
    ushort* Wffn2T = (ushort*)(ws + 139706368);     // 524,288
    ushort* WoffAwT= (ushort*)(ws + 140230656);     // 384*256*2 = 196,608
    float*  obias  = (float*)(ws + 140427264);      // 1,536
    // f32 buffers (512-aligned start)
    float* x1   = (float*)(ws + 140429312);         // 14,745,600
    float* dres = x1;
    float* xln1 = (float*)(ws + 155174912);         // 14,745,600
    float* obf  = (float*)(ws + 169920512);         // 14400*384*4 = 22,118,400
    float* x3   = obf;                              // alias (obf dead after samp_prep)
    float* samp = (float*)(ws + 192038912);         // 14,745,600
    float* xln2 = (float*)(ws + 206784512);         // 14,745,600
    ushort* h   = (ushort*)(ws + 221530112);        // 29,491,200 (bf16 hidden)
    int4*  prepI = (int4*)(ws + 251021312);         // 29,491,200
    float4* prepW = (float4*)(ws + 280512512);      // 29,491,200 -> ends 310,003,712

    const dim3 blk(256);
    const int GM = (NROWS + 127) / 128;             // 113

    // 0. weight transpose+convert to bf16 (N,K)
    conv_w_T<<<dim3(24, 8), blk, 0, stream>>>(sa_in_w, WsaInT, 256, 768);
    conv_w_T<<<dim3(8, 8), blk, 0, stream>>>(sa_out_w, WsaOutT, 256, 256);
    conv_w_T<<<dim3(8, 8), blk, 0, stream>>>(val_w, WvalT, 256, 256);
    conv_w_T<<<dim3(8, 8), blk, 0, stream>>>(dout_w, WdoutT, 256, 256);
    conv_w_T<<<dim3(32, 8), blk, 0, stream>>>(ffn_w1, Wffn1T, 256, 1024);
    conv_w_T<<<dim3(8, 32), blk, 0, stream>>>(ffn_w2, Wffn2T, 1024, 256);
    conv_w_T<<<dim3(8, 8), blk, 0, stream>>>(off_w, WoffAwT, 256, 256);
    conv_w_T<<<dim3(4, 8), blk, 0, stream>>>(aw_w, WoffAwT + 256 * 256, 256, 128);
    concat_bias<<<dim3(2), blk, 0, stream>>>(off_b, aw_b, obias);

    // 1. Q,K projections -> QKbf
    gemm_bf16<false, true, false, false, true><<<dim3(4, GM), blk, 0, stream>>>(
        qo, qpz, 256, WsaInT, sa_in_b, nullptr, QKbf, 512, NROWS, 256);
    // 2. V projection -> Vbf
    gemm_bf16<false, false, false, false, true><<<dim3(2, GM), blk, 0, stream>>>(
        qo, nullptr, 256, WsaInT + 512 * 256, sa_in_b + 512, nullptr, Vbf, 256, NROWS, 256);
    // 3. self-attention
    attn_mfma<<<dim3(15, 128), blk, 0, stream>>>(QKbf, Vbf, attnO);
    // 4. out projection + residual(qo) -> x1 f32
    gemm_bf16<true, false, false, true, false><<<dim3(2, GM), blk, 0, stream>>>(
        attnO, nullptr, 256, WsaOutT, sa_out_b, qo, x1, 256, NROWS, 256);
    // 5. LN1
    ln_kernel<<<dim3(3600), blk, 0, stream>>>(x1, n1_g, n1_b, xln1, NROWS);
    // 6. fused offsets + aw logits -> obf f32 (N=384)
    gemm_bf16<false, false, false, false, false><<<dim3(3, GM), blk, 0, stream>>>(
        xln1, nullptr, 256, WoffAwT, obias, nullptr, obf, 384, NROWS, 256);
    // 7. sampling prep (softmax fused) -> prepI/prepW
    samp_prep<<<dim3(7200), blk, 0, stream>>>(refp, obf, prepI, prepW);
    // 8. value projections per level -> Vval bf16
    gemm_bf16<false, true, false, false, true><<<dim3(2, 1250), blk, 0, stream>>>(
        feat[0], pos[0], 256, WvalT, val_b, nullptr, Vval, 256, 160000, 256);
    gemm_bf16<false, true, false, false, true><<<dim3(2, 313), blk, 0, stream>>>(
        feat[1], pos[1], 256, WvalT, val_b, nullptr, Vval + (size_t)160000 * 256, 256, 40000, 256);
    gemm_bf16<false, true, false, false, true><<<dim3(2, 79), blk, 0, stream>>>(
        feat[2], pos[2], 256, WvalT, val_b, nullptr, Vval + (size_t)200000 * 256, 256, 10000, 256);
    gemm_bf16<false, true, false, false, true><<<dim3(2, 22), blk, 0, stream>>>(
        feat[3], pos[3], 256, WvalT, val_b, nullptr, Vval + (size_t)210000 * 256, 256, 2704, 256);
    // 9. gather -> samp f32
    samp_gather<<<dim3(28800), blk, 0, stream>>>(Vval, prepI, prepW, samp);
    // 10. deform output projection + residual(xln1) -> dres f32
    gemm_bf16<false, false, false, true, false><<<dim3(2, GM), blk, 0, stream>>>(
        samp, nullptr, 256, WdoutT, dout_b, xln1, dres, 256, NROWS, 256);
    // 11. LN2
    ln_kernel<<<dim3(3600), blk, 0, stream>>>(dres, n2_g, n2_b, xln2, NROWS);
    // 12. FFN1 (relu) -> h bf16
    gemm_bf16<false, false, true, false, true><<<dim3(8, GM), blk, 0, stream>>>(
        xln2, nullptr, 256, Wffn1T, ffn_b1, nullptr, h, 1024, NROWS, 256);
    // 13. FFN2 + residual(xln2) -> x3 f32
    gemm_bf16<true, false, false, true, false><<<dim3(2, GM), blk, 0, stream>>>(
        h, nullptr, 1024, Wffn2T, ffn_b2, xln2, x3, 256, NROWS, 1024);
    // 14. LN3 -> output
    ln_kernel<<<dim3(3600), blk, 0, stream>>>(x3, n3_g, n3_b, (float*)d_out, NROWS);
}